// Round 3
// baseline (694.166 us; speedup 1.0000x reference)
//
#include <hip/hip_runtime.h>

#define SS 2048
#define DD 1024
#define DQKV 3072
#define KP 1056            // 1024 + 16 lora + 1 bias + 15 pad
#define MTOT 8192
#define QKSZ ((size_t)MTOT * DD)   // floats per q/k/v plane

typedef unsigned short us;
typedef __attribute__((ext_vector_type(8))) short bf16x8;
typedef __attribute__((ext_vector_type(4))) float f32x4;
typedef __attribute__((ext_vector_type(4))) unsigned u32x4;

__device__ __forceinline__ us f2bf(float f) {
    unsigned u = __float_as_uint(f);
    return (us)((u + 0x7fffu + ((u >> 16) & 1u)) >> 16);
}
__device__ __forceinline__ float bf2f(us h) { return __uint_as_float(((unsigned)h) << 16); }
__device__ __forceinline__ void split2(float q, us& h, us& l) {
    h = f2bf(q); l = f2bf(q - bf2f(h));
}
__device__ __forceinline__ unsigned cvtpk(float lo, float hi) {
    unsigned r;
    asm("v_cvt_pk_bf16_f32 %0, %1, %2" : "=v"(r) : "v"(lo), "v"(hi));
    return r;
}

// exact log-domain fake quant: q = sign(x)*s*2^round(log2(clip(|x|/s,2^-255,1)))
__device__ __forceinline__ float logq_exact(float x, float s) {
    float ax = fabsf(x);
    if (ax >= s) return copysignf(s, x);
    if (ax == 0.f) return copysignf(0.f, x);
    double r = (double)ax / (double)s;
    int ex;
    double mant = frexp(r, &ex);                       // [0.5,1)
    int e = (mant >= 0.70710678118654752440) ? ex : ex - 1;
    e = (e < -255) ? -255 : e;
    return copysignf(ldexpf(s, e), x);
}

__device__ __forceinline__ void gll16(const void* g, void* l) {
    __builtin_amdgcn_global_load_lds(
        (const __attribute__((address_space(1))) void*)g,
        (__attribute__((address_space(3))) void*)l, 16, 0, 0);
}

// ---------------- scales / quant / lora prep ----------------

__global__ void k_zero(unsigned* p, int n) {
    int i = blockIdx.x * 256 + threadIdx.x;
    if (i < n) p[i] = 0u;
}

__global__ void k_colmax(const float* __restrict__ x, unsigned* __restrict__ smax) {
    int c = blockIdx.x * 256 + threadIdx.x;
    int r0 = blockIdx.y * 128;
    float m = 0.f;
    for (int r = 0; r < 128; ++r) m = fmaxf(m, fabsf(x[(size_t)(r0 + r) * DD + c]));
    atomicMax(smax + c, __float_as_uint(m));
}

__global__ void k_quant_rows(const float* __restrict__ x, const unsigned* __restrict__ smax,
                             us* __restrict__ xh, us* __restrict__ xl) {
    int m = blockIdx.x, tx = threadIdx.x;
    float4 xv = ((const float4*)(x + (size_t)m * DD))[tx];
    int c = tx * 4;
    float vv[4] = {xv.x, xv.y, xv.z, xv.w};
    ushort4 qh, ql;
    us* ph = (us*)&qh; us* pl = (us*)&ql;
#pragma unroll
    for (int j = 0; j < 4; ++j) {
        float s = fmaxf(__uint_as_float(smax[c + j]), 1e-8f);
        float q = logq_exact(vv[j], s);
        split2(q, ph[j], pl[j]);
    }
    *(ushort4*)(xh + (size_t)m * KP + c) = qh;
    *(ushort4*)(xl + (size_t)m * KP + c) = ql;
    if (tx == 0) { xh[(size_t)m * KP + 1040] = 0x3F80; xl[(size_t)m * KP + 1040] = 0; }
    else if (tx < 16) { xh[(size_t)m * KP + 1040 + tx] = 0; xl[(size_t)m * KP + 1040 + tx] = 0; }
}

__global__ void k_lora_x(const float* __restrict__ x, const float* __restrict__ lA,
                         us* __restrict__ xh, us* __restrict__ xl) {
    int w = threadIdx.x >> 6, lane = threadIdx.x & 63;
    int m = blockIdx.x * 4 + w;
    const float* xr = x + (size_t)m * DD;
    float acc[16];
#pragma unroll
    for (int r = 0; r < 16; ++r) acc[r] = 0.f;
#pragma unroll
    for (int i = 0; i < 4; ++i) {
        int c0 = i * 256 + lane * 4;
        float4 xv = *(const float4*)(xr + c0);
        float xs4[4] = {xv.x, xv.y, xv.z, xv.w};
#pragma unroll
        for (int j = 0; j < 4; ++j) {
            float xs = xs4[j];
            const float4* lr = (const float4*)(lA + (size_t)(c0 + j) * 16);
            float4 a0 = lr[0], a1 = lr[1], a2 = lr[2], a3 = lr[3];
            acc[0] += xs * a0.x; acc[1] += xs * a0.y; acc[2] += xs * a0.z; acc[3] += xs * a0.w;
            acc[4] += xs * a1.x; acc[5] += xs * a1.y; acc[6] += xs * a1.z; acc[7] += xs * a1.w;
            acc[8] += xs * a2.x; acc[9] += xs * a2.y; acc[10] += xs * a2.z; acc[11] += xs * a2.w;
            acc[12] += xs * a3.x; acc[13] += xs * a3.y; acc[14] += xs * a3.z; acc[15] += xs * a3.w;
        }
    }
#pragma unroll
    for (int msk = 1; msk < 64; msk <<= 1)
#pragma unroll
        for (int r = 0; r < 16; ++r) acc[r] += __shfl_xor(acc[r], msk);
    if (lane == 0) {
#pragma unroll
        for (int r = 0; r < 16; ++r) {
            us h, l; split2(2.0f * acc[r], h, l);
            xh[(size_t)m * KP + 1024 + r] = h;
            xl[(size_t)m * KP + 1024 + r] = l;
        }
    }
}

__global__ __launch_bounds__(256) void k_quant_w(const float* __restrict__ W, const float* __restrict__ lB,
                                                 const float* __restrict__ bias,
                                                 us* __restrict__ wh, us* __restrict__ wl, int Nn) {
    __shared__ float red[4];
    int n = blockIdx.x, tx = threadIdx.x;
    int lane = tx & 63, w = tx >> 6;
    float4 wv = ((const float4*)(W + (size_t)n * DD))[tx];
    float m4 = fmaxf(fmaxf(fabsf(wv.x), fabsf(wv.y)), fmaxf(fabsf(wv.z), fabsf(wv.w)));
#pragma unroll
    for (int msk = 1; msk < 64; msk <<= 1) m4 = fmaxf(m4, __shfl_xor(m4, msk));
    if (lane == 0) red[w] = m4;
    __syncthreads();
    float s = fmaxf(fmaxf(fmaxf(red[0], red[1]), fmaxf(red[2], red[3])), 1e-8f);
    float vv[4] = {wv.x, wv.y, wv.z, wv.w};
    ushort4 qh, ql;
    us* ph = (us*)&qh; us* pl = (us*)&ql;
#pragma unroll
    for (int j = 0; j < 4; ++j) {
        float q = logq_exact(vv[j], s);
        split2(q, ph[j], pl[j]);
    }
    *(ushort4*)(wh + (size_t)n * KP + tx * 4) = qh;
    *(ushort4*)(wl + (size_t)n * KP + tx * 4) = ql;
    if (tx < 16) {
        us h, l; split2(lB[(size_t)tx * Nn + n], h, l);
        wh[(size_t)n * KP + 1024 + tx] = h; wl[(size_t)n * KP + 1024 + tx] = l;
    } else if (tx < 32) {
        us h = 0, l = 0;
        if (tx == 16) split2(bias[n], h, l);
        wh[(size_t)n * KP + 1024 + tx] = h; wl[(size_t)n * KP + 1024 + tx] = l;
    }
}

// ---------------- GEMM: C = (Ah+Al)(Bh+Bl)^T via 3 MFMA passes ----------------
// MODE 0: linear f32 C[M][Nn].  MODE 1: qkv epilogue — q plane f32 (C), v plane f32 (vbuf),
//         k plane split bf16 -> Khg/Klg [bh][s][64].

template <int MODE>
__global__ __launch_bounds__(256) void k_gemm(const us* __restrict__ Ah_, const us* __restrict__ Al_,
                                              const us* __restrict__ Bh_, const us* __restrict__ Bl_,
                                              float* __restrict__ C, int Nn,
                                              us* __restrict__ Khg, us* __restrict__ Klg,
                                              float* __restrict__ vbuf) {
    __shared__ us AhL[4096], AlL[4096], BhL[4096], BlL[4096];   // [128][32] each
    int tid = threadIdx.x;
    int bm = blockIdx.x, bn = blockIdx.y;
    int lane = tid & 63, w = tid >> 6;
    int wm = w >> 1, wn = w & 1;
    int l15 = lane & 15, l4 = lane >> 4;
    size_t aoff = ((size_t)bm * 128 + (tid >> 2)) * KP + (tid & 3) * 8;
    size_t boff = ((size_t)bn * 128 + (tid >> 2)) * KP + (tid & 3) * 8;
    f32x4 zero4 = {0.f, 0.f, 0.f, 0.f};
    f32x4 acc[4][4];
#pragma unroll
    for (int i = 0; i < 4; ++i)
#pragma unroll
        for (int j = 0; j < 4; ++j) acc[i][j] = zero4;

    for (int kt = 0; kt < KP / 32; ++kt) {
        int k0 = kt * 32;
        __syncthreads();
        gll16(Ah_ + aoff + k0, AhL + tid * 8);
        gll16(Ah_ + aoff + (size_t)64 * KP + k0, AhL + 2048 + tid * 8);
        gll16(Al_ + aoff + k0, AlL + tid * 8);
        gll16(Al_ + aoff + (size_t)64 * KP + k0, AlL + 2048 + tid * 8);
        gll16(Bh_ + boff + k0, BhL + tid * 8);
        gll16(Bh_ + boff + (size_t)64 * KP + k0, BhL + 2048 + tid * 8);
        gll16(Bl_ + boff + k0, BlL + tid * 8);
        gll16(Bl_ + boff + (size_t)64 * KP + k0, BlL + 2048 + tid * 8);
        __syncthreads();
        bf16x8 ah[4], al[4], bh[4], bl[4];
#pragma unroll
        for (int i = 0; i < 4; ++i) {
            int ro = (wm * 64 + i * 16 + l15) * 32 + l4 * 8;
            int co = (wn * 64 + i * 16 + l15) * 32 + l4 * 8;
            ah[i] = *(const bf16x8*)(AhL + ro);
            al[i] = *(const bf16x8*)(AlL + ro);
            bh[i] = *(const bf16x8*)(BhL + co);
            bl[i] = *(const bf16x8*)(BlL + co);
        }
#pragma unroll
        for (int mi = 0; mi < 4; ++mi)
#pragma unroll
            for (int ni = 0; ni < 4; ++ni) {
                acc[mi][ni] = __builtin_amdgcn_mfma_f32_16x16x32_bf16(ah[mi], bh[ni], acc[mi][ni], 0, 0, 0);
                acc[mi][ni] = __builtin_amdgcn_mfma_f32_16x16x32_bf16(ah[mi], bl[ni], acc[mi][ni], 0, 0, 0);
                acc[mi][ni] = __builtin_amdgcn_mfma_f32_16x16x32_bf16(al[mi], bh[ni], acc[mi][ni], 0, 0, 0);
            }
    }
    int plane = bn >> 3;   // MODE 1 only; block-uniform
#pragma unroll
    for (int mi = 0; mi < 4; ++mi) {
#pragma unroll
        for (int ni = 0; ni < 4; ++ni) {
            int ncol = bn * 128 + wn * 64 + ni * 16 + l15;
            size_t mbase = (size_t)bm * 128 + wm * 64 + mi * 16 + l4 * 4;
#pragma unroll
            for (int rr = 0; rr < 4; ++rr) {
                float v = acc[mi][ni][rr];
                size_t m = mbase + rr;
                if (MODE == 0) {
                    C[m * (size_t)Nn + ncol] = v;
                } else {
                    int cc = ncol & 1023;
                    if (plane == 0) {
                        C[m * DD + cc] = v;
                    } else if (plane == 2) {
                        vbuf[m * DD + cc] = v;
                    } else {
                        us hh, ll; split2(v, hh, ll);
                        size_t d = ((size_t)((m >> 11) * 16 + (cc >> 6)) * SS + (m & 2047)) * 64 + (cc & 63);
                        Khg[d] = hh; Klg[d] = ll;
                    }
                }
            }
        }
    }
}

// ---------------- V transpose+split: vbuf f32 -> vth/vtl [bh][hd][s-permuted] bf16 ----------------
// stored order per 64-s chunk: granule g (16B) of row hd holds kv {ks*32+gg*4+0..3, ks*32+16+gg*4+0..3}
// with ks=g>>2, gg=g&3  — matches PV B-fragment k-order so reads are single b128.

__global__ __launch_bounds__(256) void k_transpose_v(const float* __restrict__ vbuf,
                                                     us* __restrict__ vth, us* __restrict__ vtl) {
    __shared__ us th[64][72], tl[64][72];
    int st = blockIdx.x, bh = blockIdx.y;
    int bb = bh >> 4, h = bh & 15;
    int s0 = st * 64, tid = threadIdx.x;
    int sl = tid >> 2, c0 = (tid & 3) * 16;
    const float* src = vbuf + (size_t)(bb * SS + s0 + sl) * DD + h * 64 + c0;
#pragma unroll
    for (int j4 = 0; j4 < 4; ++j4) {
        float4 v = *(const float4*)(src + j4 * 4);
        float vv[4] = {v.x, v.y, v.z, v.w};
#pragma unroll
        for (int j = 0; j < 4; ++j) {
            us hh, ll; split2(vv[j], hh, ll);
            th[c0 + j4 * 4 + j][sl] = hh;
            tl[c0 + j4 * 4 + j][sl] = ll;
        }
    }
    __syncthreads();
#pragma unroll
    for (int p = 0; p < 2; ++p) {
        int gidx = p * 256 + tid;
        int hd = gidx >> 3, g = gidx & 7;
        int base = (g >> 2) * 32 + (g & 3) * 4;
        ushort4 a, b2, c, d2;
        a.x = th[hd][base];      a.y = th[hd][base + 1];  a.z = th[hd][base + 2];  a.w = th[hd][base + 3];
        b2.x = th[hd][base + 16]; b2.y = th[hd][base + 17]; b2.z = th[hd][base + 18]; b2.w = th[hd][base + 19];
        c.x = tl[hd][base];      c.y = tl[hd][base + 1];  c.z = tl[hd][base + 2];  c.w = tl[hd][base + 3];
        d2.x = tl[hd][base + 16]; d2.y = tl[hd][base + 17]; d2.z = tl[hd][base + 18]; d2.w = tl[hd][base + 19];
        size_t dof = ((size_t)bh * 64 + hd) * SS + s0 + g * 8;
        *(ushort4*)(vth + dof) = a;  *(ushort4*)(vth + dof + 4) = b2;
        *(ushort4*)(vtl + dof) = c;  *(ushort4*)(vtl + dof + 4) = d2;
    }
}

// ---------------- causal flash attention, hi/lo split Q,K,V,P; TK=64 ----------------
// grid (64 bh, 16 qt rev), 4 waves; wave owns 32 q rows.
// Swapped QK^T: sf = mfma(K,Q): lane l15 = q row, D rows = kv-local.

#define SCL 0.18033688011112042f   /* 0.125 * log2(e) */

__global__ __launch_bounds__(256, 4) void k_attn(const float* __restrict__ qbuf,
                                                 const us* __restrict__ Khg, const us* __restrict__ Klg,
                                                 const us* __restrict__ vth, const us* __restrict__ vtl,
                                                 float* __restrict__ o) {
    __shared__ us L[16384];   // [0]=Kh [4096]=Kl [8192]=Vh [12288]=Vl, each 64x64 bf16, XOR-8 swizzled
    int bh = blockIdx.x;
    int qt = (int)(gridDim.y - 1) - blockIdx.y;   // heavy q-tiles first
    int b = bh >> 4, h = bh & 15;
    int q0 = qt * 128;
    int tid = threadIdx.x, w = tid >> 6, lane = tid & 63;
    int l15 = lane & 15, l4 = lane >> 4;
    int qw = q0 + w * 32;
    int swz = l15 & 7;

    // Q hi/lo frags from f32 plane
    bf16x8 qh[2][2], ql[2][2];
#pragma unroll
    for (int qb = 0; qb < 2; ++qb)
#pragma unroll
        for (int hf = 0; hf < 2; ++hf) {
            const float* qp = qbuf + (size_t)(b * SS + qw + qb * 16 + l15) * DD + h * 64 + hf * 32 + l4 * 8;
            float4 a = *(const float4*)qp;
            float4 c = *(const float4*)(qp + 4);
            float vv[8] = {a.x, a.y, a.z, a.w, c.x, c.y, c.z, c.w};
            bf16x8 hq, lq;
#pragma unroll
            for (int j = 0; j < 8; ++j) {
                us hh = f2bf(vv[j]);
                hq[j] = (short)hh;
                lq[j] = (short)f2bf(vv[j] - bf2f(hh));
            }
            qh[qb][hf] = hq; ql[qb][hf] = lq;
        }

    f32x4 zero4 = {0.f, 0.f, 0.f, 0.f};
    f32x4 of[2][4];
#pragma unroll
    for (int i = 0; i < 2; ++i)
#pragma unroll
        for (int j = 0; j < 4; ++j) of[i][j] = zero4;
    float mrow[2] = {-1e30f, -1e30f}, lrow[2] = {0.f, 0.f};

    // staging offsets (thread covers 2 granules of the 64x64 tiles)
    int r0 = tid >> 3, sl0 = (tid & 7) ^ (r0 & 7);
    int g1 = tid + 256, r1 = g1 >> 3, sl1 = (g1 & 7) ^ (r1 & 7);
    int koff0 = (bh * SS + r0) * 64 + sl0 * 8;
    int koff1 = (bh * SS + r1) * 64 + sl1 * 8;
    int voff0 = (bh * 64 + r0) * SS + sl0 * 8;
    int voff1 = (bh * 64 + r1) * SS + sl1 * 8;

    int ntiles = qt * 2 + 2;
    for (int t = 0; t < ntiles; ++t) {
        int kv0 = t * 64;
        __syncthreads();
        int kadd = kv0 << 6;
        gll16(Khg + koff0 + kadd, L + tid * 8);
        gll16(Khg + koff1 + kadd, L + 2048 + tid * 8);
        gll16(Klg + koff0 + kadd, L + 4096 + tid * 8);
        gll16(Klg + koff1 + kadd, L + 6144 + tid * 8);
        gll16(vth + voff0 + kv0, L + 8192 + tid * 8);
        gll16(vth + voff1 + kv0, L + 10240 + tid * 8);
        gll16(vtl + voff0 + kv0, L + 12288 + tid * 8);
        gll16(vtl + voff1 + kv0, L + 14336 + tid * 8);
        __syncthreads();
        if (kv0 > qw + 31) continue;

        // ---- QK^T (hi*hi + hi*lo + lo*hi) ----
        f32x4 sf[4][2];
#pragma unroll
        for (int i = 0; i < 4; ++i) { sf[i][0] = zero4; sf[i][1] = zero4; }
#pragma unroll
        for (int kb = 0; kb < 4; ++kb) {
            int rbase = (kb * 16 + l15) * 64;
#pragma unroll
            for (int hf = 0; hf < 2; ++hf) {
                int off = rbase + (((hf * 4 + l4) ^ swz) * 8);
                bf16x8 kh = *(const bf16x8*)(L + off);
                bf16x8 kl = *(const bf16x8*)(L + 4096 + off);
#pragma unroll
                for (int qb = 0; qb < 2; ++qb) {
                    sf[kb][qb] = __builtin_amdgcn_mfma_f32_16x16x32_bf16(kh, qh[qb][hf], sf[kb][qb], 0, 0, 0);
                    sf[kb][qb] = __builtin_amdgcn_mfma_f32_16x16x32_bf16(kh, ql[qb][hf], sf[kb][qb], 0, 0, 0);
                    sf[kb][qb] = __builtin_amdgcn_mfma_f32_16x16x32_bf16(kl, qh[qb][hf], sf[kb][qb], 0, 0, 0);
                }
            }
        }

        // ---- softmax (exp2 domain) + P hi/lo pack ----
        bool diag = (kv0 + 63 > qw);   // wave-uniform
        u32x4 PH[2][2], PL[2][2];      // [qb][ks]; bit-identical to bf16x8 A-frags
#pragma unroll
        for (int qb = 0; qb < 2; ++qb) {
            float pv[16];
            if (diag) {
                int qg = qw + qb * 16 + l15;
#pragma unroll
                for (int kb = 0; kb < 4; ++kb)
#pragma unroll
                    for (int rr = 0; rr < 4; ++rr) {
                        int kvg = kv0 + kb * 16 + l4 * 4 + rr;
                        float sc = sf[kb][qb][rr] * SCL;
                        pv[kb * 4 + rr] = (kvg > qg) ? -1e30f : sc;
                    }
            } else {
#pragma unroll
                for (int kb = 0; kb < 4; ++kb)
#pragma unroll
                    for (int rr = 0; rr < 4; ++rr)
                        pv[kb * 4 + rr] = sf[kb][qb][rr] * SCL;
            }
            float tmax = pv[0];
#pragma unroll
            for (int i = 1; i < 16; ++i) tmax = fmaxf(tmax, pv[i]);
            tmax = fmaxf(tmax, __shfl_xor(tmax, 16));
            tmax = fmaxf(tmax, __shfl_xor(tmax, 32));
            float mnew = fmaxf(mrow[qb], tmax);
            float fac = __builtin_amdgcn_exp2f(mrow[qb] - mnew);
            mrow[qb] = mnew;
            float ps = 0.f;
#pragma unroll
            for (int i = 0; i < 16; ++i) {
                pv[i] = __builtin_amdgcn_exp2f(pv[i] - mnew);
                ps += pv[i];
            }
            ps += __shfl_xor(ps, 16); ps += __shfl_xor(ps, 32);
            lrow[qb] = lrow[qb] * fac + ps;
#pragma unroll
            for (int ks = 0; ks < 2; ++ks)
#pragma unroll
                for (int c2 = 0; c2 < 4; ++c2) {
                    float p0 = pv[ks * 8 + c2 * 2], p1 = pv[ks * 8 + c2 * 2 + 1];
                    unsigned u = cvtpk(p0, p1);
                    float h0 = __uint_as_float(u << 16);
                    float h1 = __uint_as_float(u & 0xffff0000u);
                    unsigned ul = cvtpk(p0 - h0, p1 - h1);
                    PH[qb][ks][c2] = u; PL[qb][ks][c2] = ul;
                }
            float fr0 = __shfl(fac, l4 * 4 + 0);
            float fr1 = __shfl(fac, l4 * 4 + 1);
            float fr2 = __shfl(fac, l4 * 4 + 2);
            float fr3 = __shfl(fac, l4 * 4 + 3);
#pragma unroll
            for (int hb = 0; hb < 4; ++hb) {
                of[qb][hb][0] *= fr0; of[qb][hb][1] *= fr1;
                of[qb][hb][2] *= fr2; of[qb][hb][3] *= fr3;
            }
        }

        // ---- PV (Ph*Vh + Ph*Vl + Pl*Vh) ----
#pragma unroll
        for (int hb = 0; hb < 4; ++hb) {
            int rbase = (hb * 16 + l15) * 64;
#pragma unroll
            for (int ks = 0; ks < 2; ++ks) {
                int off = rbase + (((ks * 4 + l4) ^ swz) * 8);
                bf16x8 vh = *(const bf16x8*)(L + 8192 + off);
                bf16x8 vl = *(const bf16x8*)(L + 12288 + off);
#pragma unroll
                for (int qb = 0; qb < 2; ++qb) {
                    bf16x8 pa = (bf16x8)PH[qb][ks];
                    bf16x8 pb = (bf16x8)PL[qb][ks];
                    of[qb][hb] = __builtin_amdgcn_mfma_f32_16x16x32_bf16(pa, vh, of[qb][hb], 0, 0, 0);
                    of[qb][hb] = __builtin_amdgcn_mfma_f32_16x16x32_bf16(pa, vl, of[qb][hb], 0, 0, 0);
                    of[qb][hb] = __builtin_amdgcn_mfma_f32_16x16x32_bf16(pb, vh, of[qb][hb], 0, 0, 0);
                }
            }
        }
    }

#pragma unroll
    for (int qb = 0; qb < 2; ++qb) {
        float linv = 1.f / lrow[qb];
        float f0 = __shfl(linv, l4 * 4 + 0);
        float f1 = __shfl(linv, l4 * 4 + 1);
        float f2 = __shfl(linv, l4 * 4 + 2);
        float f3 = __shfl(linv, l4 * 4 + 3);
        int qgb = qw + qb * 16 + l4 * 4;
#pragma unroll
        for (int hb = 0; hb < 4; ++hb) {
            int col = h * 64 + hb * 16 + l15;
            o[((size_t)(b * SS + qgb + 0)) * DD + col] = of[qb][hb][0] * f0;
            o[((size_t)(b * SS + qgb + 1)) * DD + col] = of[qb][hb][1] * f1;
            o[((size_t)(b * SS + qgb + 2)) * DD + col] = of[qb][hb][2] * f2;
            o[((size_t)(b * SS + qgb + 3)) * DD + col] = of[qb][hb][3] * f3;
        }
    }
}

// ---------------- launcher ----------------

extern "C" void kernel_launch(void* const* d_in, const int* in_sizes, int n_in,
                              void* d_out, int out_size, void* d_ws, size_t ws_size,
                              hipStream_t stream) {
    const float* hidden  = (const float*)d_in[0];
    const float* W_attn  = (const float*)d_in[2];
    const float* b_attn  = (const float*)d_in[3];
    const float* lA_attn = (const float*)d_in[4];
    const float* lB_attn = (const float*)d_in[5];
    const float* W_proj  = (const float*)d_in[6];
    const float* b_proj  = (const float*)d_in[7];
    const float* lA_proj = (const float*)d_in[8];
    const float* lB_proj = (const float*)d_in[9];
    float* out = (float*)d_out;

    char* ws = (char*)d_ws;
    unsigned* s1 = (unsigned*)(ws);
    unsigned* s2 = (unsigned*)(ws + 4096);
    us* xh  = (us*)(ws + 8192);                        // 17,301,504 B
    us* xl  = (us*)(ws + 8192 + 17301504);             // 17,301,504 B
    us* vth = (us*)(ws + 8192);                        // overlay xh (phase B only)
    us* vtl = (us*)(ws + 8192 + 17301504);             // overlay xl
    char* wbase = ws + 8192 + 2 * 17301504;
    us* wh1 = (us*)(wbase);
    us* wl1 = (us*)(wbase + 6488064);
    us* wh2 = (us*)(wbase + 2 * 6488064);
    us* wl2 = (us*)(wbase + 2 * 6488064 + 2162688);
    float* qkv3 = (float*)(wbase + 2 * 6488064 + 2 * 2162688);  // 96 MB region
    float* qbuf = qkv3;                                // 32 MB
    float* vbuf = qkv3 + QKSZ;                         // 32 MB
    us* Khg = (us*)(qkv3 + 2 * QKSZ);                  // 16 MB
    us* Klg = Khg + QKSZ;                              // 16 MB
    float* attn = vbuf;                                // overlay: v plane consumed by transpose

    k_zero<<<8, 256, 0, stream>>>(s1, 2048);

    // ---- qkv projection ----
    k_colmax<<<dim3(4, 64), 256, 0, stream>>>(hidden, s1);
    k_quant_rows<<<MTOT, 256, 0, stream>>>(hidden, s1, xh, xl);
    k_lora_x<<<MTOT / 4, 256, 0, stream>>>(hidden, lA_attn, xh, xl);
    k_quant_w<<<3072, 256, 0, stream>>>(W_attn, lB_attn, b_attn, wh1, wl1, 3072);
    k_quant_w<<<1024, 256, 0, stream>>>(W_proj, lB_proj, b_proj, wh2, wl2, 1024);
    k_gemm<1><<<dim3(64, 24), 256, 0, stream>>>(xh, xl, wh1, wl1, qbuf, DQKV, Khg, Klg, vbuf);

    // ---- attention ----
    k_transpose_v<<<dim3(32, 64), 256, 0, stream>>>(vbuf, vth, vtl);
    k_attn<<<dim3(64, 16), 256, 0, stream>>>(qbuf, Khg, Klg, vth, vtl, attn);

    // ---- output projection ----
    k_colmax<<<dim3(4, 64), 256, 0, stream>>>(attn, s2);
    k_quant_rows<<<MTOT, 256, 0, stream>>>(attn, s2, xh, xl);
    k_lora_x<<<MTOT / 4, 256, 0, stream>>>(attn, lA_proj, xh, xl);
    k_gemm<0><<<dim3(64, 8), 256, 0, stream>>>(xh, xl, wh2, wl2, out, DD, nullptr, nullptr, nullptr);
}

// Round 4
// 554.239 us; speedup vs baseline: 1.2525x; 1.2525x over previous
//
#include <hip/hip_runtime.h>

#define SS 2048
#define DD 1024
#define DQKV 3072
#define KP 1056            // 1024 + 16 lora + 1 bias + 15 pad
#define MTOT 8192
#define QKSZ ((size_t)MTOT * DD)   // floats per q/k/v plane

typedef unsigned short us;
typedef __attribute__((ext_vector_type(8))) short bf16x8;
typedef __attribute__((ext_vector_type(4))) float f32x4;
typedef __attribute__((ext_vector_type(4))) unsigned u32x4;

__device__ __forceinline__ us f2bf(float f) {
    unsigned u = __float_as_uint(f);
    return (us)((u + 0x7fffu + ((u >> 16) & 1u)) >> 16);
}
__device__ __forceinline__ float bf2f(us h) { return __uint_as_float(((unsigned)h) << 16); }
__device__ __forceinline__ void split2(float q, us& h, us& l) {
    h = f2bf(q); l = f2bf(q - bf2f(h));
}
__device__ __forceinline__ unsigned cvtpk(float lo, float hi) {
    unsigned r;
    asm("v_cvt_pk_bf16_f32 %0, %1, %2" : "=v"(r) : "v"(lo), "v"(hi));
    return r;
}

// exact log-domain fake quant: q = sign(x)*s*2^round(log2(clip(|x|/s,2^-255,1)))
__device__ __forceinline__ float logq_exact(float x, float s) {
    float ax = fabsf(x);
    if (ax >= s) return copysignf(s, x);
    if (ax == 0.f) return copysignf(0.f, x);
    double r = (double)ax / (double)s;
    int ex;
    double mant = frexp(r, &ex);                       // [0.5,1)
    int e = (mant >= 0.70710678118654752440) ? ex : ex - 1;
    e = (e < -255) ? -255 : e;
    return copysignf(ldexpf(s, e), x);
}

__device__ __forceinline__ void gll16(const void* g, void* l) {
    __builtin_amdgcn_global_load_lds(
        (const __attribute__((address_space(1))) void*)g,
        (__attribute__((address_space(3))) void*)l, 16, 0, 0);
}

// ---------------- scales / quant / lora prep ----------------

__global__ void k_zero(unsigned* p, int n) {
    int i = blockIdx.x * 256 + threadIdx.x;
    if (i < n) p[i] = 0u;
}

__global__ void k_colmax(const float* __restrict__ x, unsigned* __restrict__ smax) {
    int c = blockIdx.x * 256 + threadIdx.x;
    int r0 = blockIdx.y * 128;
    float m = 0.f;
    for (int r = 0; r < 128; ++r) m = fmaxf(m, fabsf(x[(size_t)(r0 + r) * DD + c]));
    atomicMax(smax + c, __float_as_uint(m));
}

__global__ void k_quant_rows(const float* __restrict__ x, const unsigned* __restrict__ smax,
                             us* __restrict__ xh, us* __restrict__ xl) {
    int m = blockIdx.x, tx = threadIdx.x;
    float4 xv = ((const float4*)(x + (size_t)m * DD))[tx];
    int c = tx * 4;
    float vv[4] = {xv.x, xv.y, xv.z, xv.w};
    ushort4 qh, ql;
    us* ph = (us*)&qh; us* pl = (us*)&ql;
#pragma unroll
    for (int j = 0; j < 4; ++j) {
        float s = fmaxf(__uint_as_float(smax[c + j]), 1e-8f);
        float q = logq_exact(vv[j], s);
        split2(q, ph[j], pl[j]);
    }
    *(ushort4*)(xh + (size_t)m * KP + c) = qh;
    *(ushort4*)(xl + (size_t)m * KP + c) = ql;
    if (tx == 0) { xh[(size_t)m * KP + 1040] = 0x3F80; xl[(size_t)m * KP + 1040] = 0; }
    else if (tx < 16) { xh[(size_t)m * KP + 1040 + tx] = 0; xl[(size_t)m * KP + 1040 + tx] = 0; }
}

__global__ void k_lora_x(const float* __restrict__ x, const float* __restrict__ lA,
                         us* __restrict__ xh, us* __restrict__ xl) {
    int w = threadIdx.x >> 6, lane = threadIdx.x & 63;
    int m = blockIdx.x * 4 + w;
    const float* xr = x + (size_t)m * DD;
    float acc[16];
#pragma unroll
    for (int r = 0; r < 16; ++r) acc[r] = 0.f;
#pragma unroll
    for (int i = 0; i < 4; ++i) {
        int c0 = i * 256 + lane * 4;
        float4 xv = *(const float4*)(xr + c0);
        float xs4[4] = {xv.x, xv.y, xv.z, xv.w};
#pragma unroll
        for (int j = 0; j < 4; ++j) {
            float xs = xs4[j];
            const float4* lr = (const float4*)(lA + (size_t)(c0 + j) * 16);
            float4 a0 = lr[0], a1 = lr[1], a2 = lr[2], a3 = lr[3];
            acc[0] += xs * a0.x; acc[1] += xs * a0.y; acc[2] += xs * a0.z; acc[3] += xs * a0.w;
            acc[4] += xs * a1.x; acc[5] += xs * a1.y; acc[6] += xs * a1.z; acc[7] += xs * a1.w;
            acc[8] += xs * a2.x; acc[9] += xs * a2.y; acc[10] += xs * a2.z; acc[11] += xs * a2.w;
            acc[12] += xs * a3.x; acc[13] += xs * a3.y; acc[14] += xs * a3.z; acc[15] += xs * a3.w;
        }
    }
#pragma unroll
    for (int msk = 1; msk < 64; msk <<= 1)
#pragma unroll
        for (int r = 0; r < 16; ++r) acc[r] += __shfl_xor(acc[r], msk);
    if (lane == 0) {
#pragma unroll
        for (int r = 0; r < 16; ++r) {
            us h, l; split2(2.0f * acc[r], h, l);
            xh[(size_t)m * KP + 1024 + r] = h;
            xl[(size_t)m * KP + 1024 + r] = l;
        }
    }
}

__global__ __launch_bounds__(256) void k_quant_w(const float* __restrict__ W, const float* __restrict__ lB,
                                                 const float* __restrict__ bias,
                                                 us* __restrict__ wh, us* __restrict__ wl, int Nn) {
    __shared__ float red[4];
    int n = blockIdx.x, tx = threadIdx.x;
    int lane = tx & 63, w = tx >> 6;
    float4 wv = ((const float4*)(W + (size_t)n * DD))[tx];
    float m4 = fmaxf(fmaxf(fabsf(wv.x), fabsf(wv.y)), fmaxf(fabsf(wv.z), fabsf(wv.w)));
#pragma unroll
    for (int msk = 1; msk < 64; msk <<= 1) m4 = fmaxf(m4, __shfl_xor(m4, msk));
    if (lane == 0) red[w] = m4;
    __syncthreads();
    float s = fmaxf(fmaxf(fmaxf(red[0], red[1]), fmaxf(red[2], red[3])), 1e-8f);
    float vv[4] = {wv.x, wv.y, wv.z, wv.w};
    ushort4 qh, ql;
    us* ph = (us*)&qh; us* pl = (us*)&ql;
#pragma unroll
    for (int j = 0; j < 4; ++j) {
        float q = logq_exact(vv[j], s);
        split2(q, ph[j], pl[j]);
    }
    *(ushort4*)(wh + (size_t)n * KP + tx * 4) = qh;
    *(ushort4*)(wl + (size_t)n * KP + tx * 4) = ql;
    if (tx < 16) {
        us h, l; split2(lB[(size_t)tx * Nn + n], h, l);
        wh[(size_t)n * KP + 1024 + tx] = h; wl[(size_t)n * KP + 1024 + tx] = l;
    } else if (tx < 32) {
        us h = 0, l = 0;
        if (tx == 16) split2(bias[n], h, l);
        wh[(size_t)n * KP + 1024 + tx] = h; wl[(size_t)n * KP + 1024 + tx] = l;
    }
}

// ---------------- GEMM: C = (Ah+Al)(Bh+Bl)^T via 3 MFMA passes ----------------
// MODE 0: linear f32 C[M][Nn].  MODE 1: qkv epilogue — q plane f32 (C), v plane f32 (vbuf),
//         k plane split bf16 -> Khg/Klg [bh][s][64].

template <int MODE>
__global__ __launch_bounds__(256) void k_gemm(const us* __restrict__ Ah_, const us* __restrict__ Al_,
                                              const us* __restrict__ Bh_, const us* __restrict__ Bl_,
                                              float* __restrict__ C, int Nn,
                                              us* __restrict__ Khg, us* __restrict__ Klg,
                                              float* __restrict__ vbuf) {
    __shared__ us AhL[4096], AlL[4096], BhL[4096], BlL[4096];   // [128][32] each
    int tid = threadIdx.x;
    int bm = blockIdx.x, bn = blockIdx.y;
    int lane = tid & 63, w = tid >> 6;
    int wm = w >> 1, wn = w & 1;
    int l15 = lane & 15, l4 = lane >> 4;
    size_t aoff = ((size_t)bm * 128 + (tid >> 2)) * KP + (tid & 3) * 8;
    size_t boff = ((size_t)bn * 128 + (tid >> 2)) * KP + (tid & 3) * 8;
    f32x4 zero4 = {0.f, 0.f, 0.f, 0.f};
    f32x4 acc[4][4];
#pragma unroll
    for (int i = 0; i < 4; ++i)
#pragma unroll
        for (int j = 0; j < 4; ++j) acc[i][j] = zero4;

    for (int kt = 0; kt < KP / 32; ++kt) {
        int k0 = kt * 32;
        __syncthreads();
        gll16(Ah_ + aoff + k0, AhL + tid * 8);
        gll16(Ah_ + aoff + (size_t)64 * KP + k0, AhL + 2048 + tid * 8);
        gll16(Al_ + aoff + k0, AlL + tid * 8);
        gll16(Al_ + aoff + (size_t)64 * KP + k0, AlL + 2048 + tid * 8);
        gll16(Bh_ + boff + k0, BhL + tid * 8);
        gll16(Bh_ + boff + (size_t)64 * KP + k0, BhL + 2048 + tid * 8);
        gll16(Bl_ + boff + k0, BlL + tid * 8);
        gll16(Bl_ + boff + (size_t)64 * KP + k0, BlL + 2048 + tid * 8);
        __syncthreads();
        bf16x8 ah[4], al[4], bh[4], bl[4];
#pragma unroll
        for (int i = 0; i < 4; ++i) {
            int ro = (wm * 64 + i * 16 + l15) * 32 + l4 * 8;
            int co = (wn * 64 + i * 16 + l15) * 32 + l4 * 8;
            ah[i] = *(const bf16x8*)(AhL + ro);
            al[i] = *(const bf16x8*)(AlL + ro);
            bh[i] = *(const bf16x8*)(BhL + co);
            bl[i] = *(const bf16x8*)(BlL + co);
        }
#pragma unroll
        for (int mi = 0; mi < 4; ++mi)
#pragma unroll
            for (int ni = 0; ni < 4; ++ni) {
                acc[mi][ni] = __builtin_amdgcn_mfma_f32_16x16x32_bf16(ah[mi], bh[ni], acc[mi][ni], 0, 0, 0);
                acc[mi][ni] = __builtin_amdgcn_mfma_f32_16x16x32_bf16(ah[mi], bl[ni], acc[mi][ni], 0, 0, 0);
                acc[mi][ni] = __builtin_amdgcn_mfma_f32_16x16x32_bf16(al[mi], bh[ni], acc[mi][ni], 0, 0, 0);
            }
    }
    int plane = bn >> 3;   // MODE 1 only; block-uniform
#pragma unroll
    for (int mi = 0; mi < 4; ++mi) {
#pragma unroll
        for (int ni = 0; ni < 4; ++ni) {
            int ncol = bn * 128 + wn * 64 + ni * 16 + l15;
            size_t mbase = (size_t)bm * 128 + wm * 64 + mi * 16 + l4 * 4;
#pragma unroll
            for (int rr = 0; rr < 4; ++rr) {
                float v = acc[mi][ni][rr];
                size_t m = mbase + rr;
                if (MODE == 0) {
                    C[m * (size_t)Nn + ncol] = v;
                } else {
                    int cc = ncol & 1023;
                    if (plane == 0) {
                        C[m * DD + cc] = v;
                    } else if (plane == 2) {
                        vbuf[m * DD + cc] = v;
                    } else {
                        us hh, ll; split2(v, hh, ll);
                        size_t d = ((size_t)((m >> 11) * 16 + (cc >> 6)) * SS + (m & 2047)) * 64 + (cc & 63);
                        Khg[d] = hh; Klg[d] = ll;
                    }
                }
            }
        }
    }
}

// ---------------- V transpose+split: vbuf f32 -> vth/vtl [bh][hd][s-permuted] bf16 ----------------
// stored order per 64-s chunk: granule g (16B) of row hd holds kv {ks*32+gg*4+0..3, ks*32+16+gg*4+0..3}
// with ks=g>>2, gg=g&3  — matches PV B-fragment k-order so reads are single b128.

__global__ __launch_bounds__(256) void k_transpose_v(const float* __restrict__ vbuf,
                                                     us* __restrict__ vth, us* __restrict__ vtl) {
    __shared__ us th[64][72], tl[64][72];
    int st = blockIdx.x, bh = blockIdx.y;
    int bb = bh >> 4, h = bh & 15;
    int s0 = st * 64, tid = threadIdx.x;
    int sl = tid >> 2, c0 = (tid & 3) * 16;
    const float* src = vbuf + (size_t)(bb * SS + s0 + sl) * DD + h * 64 + c0;
#pragma unroll
    for (int j4 = 0; j4 < 4; ++j4) {
        float4 v = *(const float4*)(src + j4 * 4);
        float vv[4] = {v.x, v.y, v.z, v.w};
#pragma unroll
        for (int j = 0; j < 4; ++j) {
            us hh, ll; split2(vv[j], hh, ll);
            th[c0 + j4 * 4 + j][sl] = hh;
            tl[c0 + j4 * 4 + j][sl] = ll;
        }
    }
    __syncthreads();
#pragma unroll
    for (int p = 0; p < 2; ++p) {
        int gidx = p * 256 + tid;
        int hd = gidx >> 3, g = gidx & 7;
        int base = (g >> 2) * 32 + (g & 3) * 4;
        ushort4 a, b2, c, d2;
        a.x = th[hd][base];      a.y = th[hd][base + 1];  a.z = th[hd][base + 2];  a.w = th[hd][base + 3];
        b2.x = th[hd][base + 16]; b2.y = th[hd][base + 17]; b2.z = th[hd][base + 18]; b2.w = th[hd][base + 19];
        c.x = tl[hd][base];      c.y = tl[hd][base + 1];  c.z = tl[hd][base + 2];  c.w = tl[hd][base + 3];
        d2.x = tl[hd][base + 16]; d2.y = tl[hd][base + 17]; d2.z = tl[hd][base + 18]; d2.w = tl[hd][base + 19];
        size_t dof = ((size_t)bh * 64 + hd) * SS + s0 + g * 8;
        *(ushort4*)(vth + dof) = a;  *(ushort4*)(vth + dof + 4) = b2;
        *(ushort4*)(vtl + dof) = c;  *(ushort4*)(vtl + dof + 4) = d2;
    }
}

// ---------------- causal flash attention, hi/lo split Q,K,V,P; TK=64, double-buffered ----------------
// grid (64 bh, 16 qt rev), 4 waves; wave owns 32 q rows.
// Swapped QK^T: sf = mfma(K,Q): lane l15 = q row, D rows = kv-local.
// 2-phase pipeline: STAGE(t+1) issued before compute(t); ONE barrier per tile.

#define SCL 0.18033688011112042f   /* 0.125 * log2(e) */

__global__ __launch_bounds__(256, 2) void k_attn(const float* __restrict__ qbuf,
                                                 const us* __restrict__ Khg, const us* __restrict__ Klg,
                                                 const us* __restrict__ vth, const us* __restrict__ vtl,
                                                 float* __restrict__ o) {
    __shared__ us L[2][16384];  // per buf: [0]=Kh [4096]=Kl [8192]=Vh [12288]=Vl, 64x64 bf16, XOR-8 swz
    int bh = blockIdx.x;
    int qt = (int)(gridDim.y - 1) - blockIdx.y;   // heavy q-tiles first
    int b = bh >> 4, h = bh & 15;
    int q0 = qt * 128;
    int tid = threadIdx.x, w = tid >> 6, lane = tid & 63;
    int l15 = lane & 15, l4 = lane >> 4;
    int qw = q0 + w * 32;
    int swz = l15 & 7;

    // Q hi/lo frags from f32 plane
    bf16x8 qh[2][2], ql[2][2];
#pragma unroll
    for (int qb = 0; qb < 2; ++qb)
#pragma unroll
        for (int hf = 0; hf < 2; ++hf) {
            const float* qp = qbuf + (size_t)(b * SS + qw + qb * 16 + l15) * DD + h * 64 + hf * 32 + l4 * 8;
            float4 a = *(const float4*)qp;
            float4 c = *(const float4*)(qp + 4);
            float vv[8] = {a.x, a.y, a.z, a.w, c.x, c.y, c.z, c.w};
            bf16x8 hq, lq;
#pragma unroll
            for (int j = 0; j < 8; ++j) {
                us hh = f2bf(vv[j]);
                hq[j] = (short)hh;
                lq[j] = (short)f2bf(vv[j] - bf2f(hh));
            }
            qh[qb][hf] = hq; ql[qb][hf] = lq;
        }

    f32x4 zero4 = {0.f, 0.f, 0.f, 0.f};
    f32x4 of[2][4];
#pragma unroll
    for (int i = 0; i < 2; ++i)
#pragma unroll
        for (int j = 0; j < 4; ++j) of[i][j] = zero4;
    float mrow[2] = {-1e30f, -1e30f}, lrow[2] = {0.f, 0.f};

    // staging offsets (thread covers 2 granules of each 64x64 tile)
    int r0 = tid >> 3, sl0 = (tid & 7) ^ (r0 & 7);
    int g1 = tid + 256, r1 = g1 >> 3, sl1 = (g1 & 7) ^ (r1 & 7);
    int koff0 = (bh * SS + r0) * 64 + sl0 * 8;
    int koff1 = (bh * SS + r1) * 64 + sl1 * 8;
    int voff0 = (bh * 64 + r0) * SS + sl0 * 8;
    int voff1 = (bh * 64 + r1) * SS + sl1 * 8;

    int ntiles = qt * 2 + 2;

#define STAGE(buf, tt)                                           \
    do {                                                         \
        int kv_ = (tt) * 64;                                     \
        us* D_ = &L[(buf)][0];                                   \
        int kadd_ = kv_ << 6;                                    \
        gll16(Khg + koff0 + kadd_, D_ + tid * 8);                \
        gll16(Khg + koff1 + kadd_, D_ + 2048 + tid * 8);         \
        gll16(Klg + koff0 + kadd_, D_ + 4096 + tid * 8);         \
        gll16(Klg + koff1 + kadd_, D_ + 6144 + tid * 8);         \
        gll16(vth + voff0 + kv_, D_ + 8192 + tid * 8);           \
        gll16(vth + voff1 + kv_, D_ + 10240 + tid * 8);          \
        gll16(vtl + voff0 + kv_, D_ + 12288 + tid * 8);          \
        gll16(vtl + voff1 + kv_, D_ + 14336 + tid * 8);          \
    } while (0)

    STAGE(0, 0);
    __syncthreads();   // tile 0 ready (compiler drains vmcnt before s_barrier)
    int cur = 0;

    for (int t = 0; t < ntiles; ++t) {
        int kv0 = t * 64;
        if (t + 1 < ntiles) STAGE(cur ^ 1, t + 1);

        if (kv0 <= qw + 31) {
            const us* Lc = &L[cur][0];

            // ---- QK^T (hi*hi + hi*lo + lo*hi) ----
            f32x4 sf[4][2];
#pragma unroll
            for (int i = 0; i < 4; ++i) { sf[i][0] = zero4; sf[i][1] = zero4; }
            __builtin_amdgcn_s_setprio(1);
#pragma unroll
            for (int kb = 0; kb < 4; ++kb) {
                int rbase = (kb * 16 + l15) * 64;
#pragma unroll
                for (int hf = 0; hf < 2; ++hf) {
                    int off = rbase + (((hf * 4 + l4) ^ swz) * 8);
                    bf16x8 kh = *(const bf16x8*)(Lc + off);
                    bf16x8 kl = *(const bf16x8*)(Lc + 4096 + off);
#pragma unroll
                    for (int qb = 0; qb < 2; ++qb) {
                        sf[kb][qb] = __builtin_amdgcn_mfma_f32_16x16x32_bf16(kh, qh[qb][hf], sf[kb][qb], 0, 0, 0);
                        sf[kb][qb] = __builtin_amdgcn_mfma_f32_16x16x32_bf16(kh, ql[qb][hf], sf[kb][qb], 0, 0, 0);
                        sf[kb][qb] = __builtin_amdgcn_mfma_f32_16x16x32_bf16(kl, qh[qb][hf], sf[kb][qb], 0, 0, 0);
                    }
                }
            }
            __builtin_amdgcn_s_setprio(0);

            // ---- softmax (exp2 domain) + P hi/lo pack ----
            bool diag = (kv0 + 63 > qw);   // wave-uniform
            u32x4 PH[2][2], PL[2][2];      // [qb][ks]; bit-identical to bf16x8 A-frags
#pragma unroll
            for (int qb = 0; qb < 2; ++qb) {
                float pv[16];
                if (diag) {
                    int qg = qw + qb * 16 + l15;
#pragma unroll
                    for (int kb = 0; kb < 4; ++kb)
#pragma unroll
                        for (int rr = 0; rr < 4; ++rr) {
                            int kvg = kv0 + kb * 16 + l4 * 4 + rr;
                            float sc = sf[kb][qb][rr] * SCL;
                            pv[kb * 4 + rr] = (kvg > qg) ? -1e30f : sc;
                        }
                } else {
#pragma unroll
                    for (int kb = 0; kb < 4; ++kb)
#pragma unroll
                        for (int rr = 0; rr < 4; ++rr)
                            pv[kb * 4 + rr] = sf[kb][qb][rr] * SCL;
                }
                float tmax = pv[0];
#pragma unroll
                for (int i = 1; i < 16; ++i) tmax = fmaxf(tmax, pv[i]);
                tmax = fmaxf(tmax, __shfl_xor(tmax, 16));
                tmax = fmaxf(tmax, __shfl_xor(tmax, 32));
                float mnew = fmaxf(mrow[qb], tmax);
                float fac = __builtin_amdgcn_exp2f(mrow[qb] - mnew);
                mrow[qb] = mnew;
                float ps = 0.f;
#pragma unroll
                for (int i = 0; i < 16; ++i) {
                    pv[i] = __builtin_amdgcn_exp2f(pv[i] - mnew);
                    ps += pv[i];
                }
                ps += __shfl_xor(ps, 16); ps += __shfl_xor(ps, 32);
                lrow[qb] = lrow[qb] * fac + ps;
#pragma unroll
                for (int ks = 0; ks < 2; ++ks)
#pragma unroll
                    for (int c2 = 0; c2 < 4; ++c2) {
                        float p0 = pv[ks * 8 + c2 * 2], p1 = pv[ks * 8 + c2 * 2 + 1];
                        unsigned u = cvtpk(p0, p1);
                        float h0 = __uint_as_float(u << 16);
                        float h1 = __uint_as_float(u & 0xffff0000u);
                        unsigned ul = cvtpk(p0 - h0, p1 - h1);
                        PH[qb][ks][c2] = u; PL[qb][ks][c2] = ul;
                    }
                float fr0 = __shfl(fac, l4 * 4 + 0);
                float fr1 = __shfl(fac, l4 * 4 + 1);
                float fr2 = __shfl(fac, l4 * 4 + 2);
                float fr3 = __shfl(fac, l4 * 4 + 3);
#pragma unroll
                for (int hb = 0; hb < 4; ++hb) {
                    of[qb][hb][0] *= fr0; of[qb][hb][1] *= fr1;
                    of[qb][hb][2] *= fr2; of[qb][hb][3] *= fr3;
                }
            }

            // ---- PV (Ph*Vh + Ph*Vl + Pl*Vh) ----
            __builtin_amdgcn_s_setprio(1);
#pragma unroll
            for (int hb = 0; hb < 4; ++hb) {
                int rbase = (hb * 16 + l15) * 64;
#pragma unroll
                for (int ks = 0; ks < 2; ++ks) {
                    int off = rbase + (((ks * 4 + l4) ^ swz) * 8);
                    bf16x8 vh = *(const bf16x8*)(Lc + 8192 + off);
                    bf16x8 vl = *(const bf16x8*)(Lc + 12288 + off);
#pragma unroll
                    for (int qb = 0; qb < 2; ++qb) {
                        bf16x8 pa = (bf16x8)PH[qb][ks];
                        bf16x8 pb = (bf16x8)PL[qb][ks];
                        of[qb][hb] = __builtin_amdgcn_mfma_f32_16x16x32_bf16(pa, vh, of[qb][hb], 0, 0, 0);
                        of[qb][hb] = __builtin_amdgcn_mfma_f32_16x16x32_bf16(pa, vl, of[qb][hb], 0, 0, 0);
                        of[qb][hb] = __builtin_amdgcn_mfma_f32_16x16x32_bf16(pb, vh, of[qb][hb], 0, 0, 0);
                    }
                }
            }
            __builtin_amdgcn_s_setprio(0);
        }

        __syncthreads();   // drains tile t+1 loads; releases L[cur] for restaging
        cur ^= 1;
    }
#undef STAGE

#pragma unroll
    for (int qb = 0; qb < 2; ++qb) {
        float linv = 1.f / lrow[qb];
        float f0 = __shfl(linv, l4 * 4 + 0);
        float f1 = __shfl(linv, l4 * 4 + 1);
        float f2 = __shfl(linv, l4 * 4 + 2);
        float f3 = __shfl(linv, l4 * 4 + 3);
        int qgb = qw + qb * 16 + l4 * 4;
#pragma unroll
        for (int hb = 0; hb < 4; ++hb) {
            int col = h * 64 + hb * 16 + l15;
            o[((size_t)(b * SS + qgb + 0)) * DD + col] = of[qb][hb][0] * f0;
            o[((size_t)(b * SS + qgb + 1)) * DD + col] = of[qb][hb][1] * f1;
            o[((size_t)(b * SS + qgb + 2)) * DD + col] = of[qb][hb][2] * f2;
            o[((size_t)(b * SS + qgb + 3)) * DD + col] = of[qb][hb][3] * f3;
        }
    }
}

// ---------------- launcher ----------------

extern "C" void kernel_launch(void* const* d_in, const int* in_sizes, int n_in,
                              void* d_out, int out_size, void* d_ws, size_t ws_size,
                              hipStream_t stream) {
    const float* hidden  = (const float*)d_in[0];
    const float* W_attn  = (const float*)d_in[2];
    const float* b_attn  = (const float*)d_in[3];
    const float* lA_attn = (const float*)d_in[4];
    const float* lB_attn = (const float*)d_in[5];
    const float* W_proj  = (const float*)d_in[6];
    const float* b_proj  = (const float*)d_in[7];
    const float* lA_proj = (const float*)d_in[8];
    const float* lB_proj = (const float*)d_in[9];
    float* out = (float*)d_out;

    char* ws = (char*)d_ws;
    unsigned* s1 = (unsigned*)(ws);
    unsigned* s2 = (unsigned*)(ws + 4096);
    us* xh  = (us*)(ws + 8192);                        // 17,301,504 B
    us* xl  = (us*)(ws + 8192 + 17301504);             // 17,301,504 B
    us* vth = (us*)(ws + 8192);                        // overlay xh (phase B only)
    us* vtl = (us*)(ws + 8192 + 17301504);             // overlay xl
    char* wbase = ws + 8192 + 2 * 17301504;
    us* wh1 = (us*)(wbase);
    us* wl1 = (us*)(wbase + 6488064);
    us* wh2 = (us*)(wbase + 2 * 6488064);
    us* wl2 = (us*)(wbase + 2 * 6488064 + 2162688);
    float* qkv3 = (float*)(wbase + 2 * 6488064 + 2 * 2162688);  // 96 MB region
    float* qbuf = qkv3;                                // 32 MB
    float* vbuf = qkv3 + QKSZ;                         // 32 MB
    us* Khg = (us*)(qkv3 + 2 * QKSZ);                  // 16 MB
    us* Klg = Khg + QKSZ;                              // 16 MB
    float* attn = vbuf;                                // overlay: v plane consumed by transpose

    k_zero<<<8, 256, 0, stream>>>(s1, 2048);

    // ---- qkv projection ----
    k_colmax<<<dim3(4, 64), 256, 0, stream>>>(hidden, s1);
    k_quant_rows<<<MTOT, 256, 0, stream>>>(hidden, s1, xh, xl);
    k_lora_x<<<MTOT / 4, 256, 0, stream>>>(hidden, lA_attn, xh, xl);
    k_quant_w<<<3072, 256, 0, stream>>>(W_attn, lB_attn, b_attn, wh1, wl1, 3072);
    k_quant_w<<<1024, 256, 0, stream>>>(W_proj, lB_proj, b_proj, wh2, wl2, 1024);
    k_gemm<1><<<dim3(64, 24), 256, 0, stream>>>(xh, xl, wh1, wl1, qbuf, DQKV, Khg, Klg, vbuf);

    // ---- attention ----
    k_transpose_v<<<dim3(32, 64), 256, 0, stream>>>(vbuf, vth, vtl);
    k_attn<<<dim3(64, 16), 256, 0, stream>>>(qbuf, Khg, Klg, vth, vtl, attn);

    // ---- output projection ----
    k_colmax<<<dim3(4, 64), 256, 0, stream>>>(attn, s2);
    k_quant_rows<<<MTOT, 256, 0, stream>>>(attn, s2, xh, xl);
    k_lora_x<<<MTOT / 4, 256, 0, stream>>>(attn, lA_proj, xh, xl);
    k_gemm<0><<<dim3(64, 8), 256, 0, stream>>>(xh, xl, wh2, wl2, out, DD, nullptr, nullptr, nullptr);
}

// Round 5
// 531.492 us; speedup vs baseline: 1.3061x; 1.0428x over previous
//
#include <hip/hip_runtime.h>

#define SS 2048
#define DD 1024
#define DQKV 3072
#define KP 1088            // 1024 + 16 lora-hi + 16 lora-lo + 1 bias + 31 pad
#define NT (KP / 32)       // 34 K-steps
#define MTOT 8192
#define QKSZ ((size_t)MTOT * DD)   // floats per q/k/v plane

typedef unsigned short us;
typedef __attribute__((ext_vector_type(8))) short bf16x8;
typedef __attribute__((ext_vector_type(4))) float f32x4;
typedef __attribute__((ext_vector_type(4))) unsigned u32x4;

__device__ __forceinline__ us f2bf(float f) {
    unsigned u = __float_as_uint(f);
    return (us)((u + 0x7fffu + ((u >> 16) & 1u)) >> 16);
}
__device__ __forceinline__ float bf2f(us h) { return __uint_as_float(((unsigned)h) << 16); }
__device__ __forceinline__ void split2(float q, us& h, us& l) {
    h = f2bf(q); l = f2bf(q - bf2f(h));
}
__device__ __forceinline__ unsigned cvtpk(float lo, float hi) {
    unsigned r;
    asm("v_cvt_pk_bf16_f32 %0, %1, %2" : "=v"(r) : "v"(lo), "v"(hi));
    return r;
}

// exact log-domain fake quant level: e = round(log2(clip(|x|/s, 2^-255, 1))), boundary in double
__device__ __forceinline__ int logq_e(float ax, float s) {
    int e = 0;
    if (ax < s) {
        double r = (double)ax / (double)s;
        int ex;
        double mant = frexp(r, &ex);                   // [0.5,1)
        e = (mant >= 0.70710678118654752440) ? ex : ex - 1;
        e = (e < -255) ? -255 : e;
    }
    return e;
}
__device__ __forceinline__ float logq_exact(float x, float s) {
    float ax = fabsf(x);
    if (ax == 0.f) return copysignf(0.f, x);
    return copysignf(ldexpf(s, logq_e(ax, s)), x);
}

__device__ __forceinline__ void gll16(const void* g, void* l) {
    __builtin_amdgcn_global_load_lds(
        (const __attribute__((address_space(1))) void*)g,
        (__attribute__((address_space(3))) void*)l, 16, 0, 0);
}

// ---------------- scales / quant / lora prep ----------------

__global__ void k_zero(unsigned* p, int n) {
    int i = blockIdx.x * 256 + threadIdx.x;
    if (i < n) p[i] = 0u;
}

__global__ void k_colmax(const float* __restrict__ x, unsigned* __restrict__ smax) {
    int c = blockIdx.x * 256 + threadIdx.x;
    int r0 = blockIdx.y * 128;
    float m = 0.f;
    for (int r = 0; r < 128; ++r) m = fmaxf(m, fabsf(x[(size_t)(r0 + r) * DD + c]));
    atomicMax(smax + c, __float_as_uint(m));
}

// quantize row -> EXACT bf16 rep Ah = sign * bf16(s) * 2^e  (xq = Ah*(1+rho_c) exactly)
__global__ void k_quant_rows(const float* __restrict__ x, const unsigned* __restrict__ smax,
                             us* __restrict__ xq) {
    int m = blockIdx.x, tx = threadIdx.x;
    float4 xv = ((const float4*)(x + (size_t)m * DD))[tx];
    int c = tx * 4;
    float vv[4] = {xv.x, xv.y, xv.z, xv.w};
    ushort4 qh;
    us* ph = (us*)&qh;
#pragma unroll
    for (int j = 0; j < 4; ++j) {
        float s = fmaxf(__uint_as_float(smax[c + j]), 1e-8f);
        float sh = bf2f(f2bf(s));
        float ax = fabsf(vv[j]);
        if (ax == 0.f) ph[j] = (us)((__float_as_uint(vv[j]) >> 16) & 0x8000u);
        else ph[j] = f2bf(copysignf(ldexpf(sh, logq_e(ax, s)), vv[j]));
    }
    *(ushort4*)(xq + (size_t)m * KP + c) = qh;
    if (tx == 0) xq[(size_t)m * KP + 1056] = 0x3F80;          // bias col = 1.0
    else if (tx < 32) xq[(size_t)m * KP + 1056 + tx] = 0;     // pad 1057..1087
}

// lora cols: 1024+r = hi(2*x@lA), 1040+r = lo  (exact pair vs duplicated lB cols)
__global__ void k_lora_x(const float* __restrict__ x, const float* __restrict__ lA,
                         us* __restrict__ xq) {
    int w = threadIdx.x >> 6, lane = threadIdx.x & 63;
    int m = blockIdx.x * 4 + w;
    const float* xr = x + (size_t)m * DD;
    float acc[16];
#pragma unroll
    for (int r = 0; r < 16; ++r) acc[r] = 0.f;
#pragma unroll
    for (int i = 0; i < 4; ++i) {
        int c0 = i * 256 + lane * 4;
        float4 xv = *(const float4*)(xr + c0);
        float xs4[4] = {xv.x, xv.y, xv.z, xv.w};
#pragma unroll
        for (int j = 0; j < 4; ++j) {
            float xs = xs4[j];
            const float4* lr = (const float4*)(lA + (size_t)(c0 + j) * 16);
            float4 a0 = lr[0], a1 = lr[1], a2 = lr[2], a3 = lr[3];
            acc[0] += xs * a0.x; acc[1] += xs * a0.y; acc[2] += xs * a0.z; acc[3] += xs * a0.w;
            acc[4] += xs * a1.x; acc[5] += xs * a1.y; acc[6] += xs * a1.z; acc[7] += xs * a1.w;
            acc[8] += xs * a2.x; acc[9] += xs * a2.y; acc[10] += xs * a2.z; acc[11] += xs * a2.w;
            acc[12] += xs * a3.x; acc[13] += xs * a3.y; acc[14] += xs * a3.z; acc[15] += xs * a3.w;
        }
    }
#pragma unroll
    for (int msk = 1; msk < 64; msk <<= 1)
#pragma unroll
        for (int r = 0; r < 16; ++r) acc[r] += __shfl_xor(acc[r], msk);
    if (lane == 0) {
#pragma unroll
        for (int r = 0; r < 16; ++r) {
            us h, l; split2(2.0f * acc[r], h, l);
            xq[(size_t)m * KP + 1024 + r] = h;
            xq[(size_t)m * KP + 1040 + r] = l;
        }
    }
}

// weight quant + fold activation-scale residual: W' = Wq*(1+rho_c); split hi/lo.
// tail cols: [1024..1039]=lB hi-pair-slot, [1040..1055]=lB duplicate, 1056=bias, rest 0 (all h/l split)
__global__ __launch_bounds__(256) void k_quant_w(const float* __restrict__ W, const float* __restrict__ lB,
                                                 const float* __restrict__ bias,
                                                 const unsigned* __restrict__ smax,
                                                 us* __restrict__ wh, us* __restrict__ wl, int Nn) {
    __shared__ float red[4];
    int n = blockIdx.x, tx = threadIdx.x;
    int lane = tx & 63, w = tx >> 6;
    float4 wv = ((const float4*)(W + (size_t)n * DD))[tx];
    float m4 = fmaxf(fmaxf(fabsf(wv.x), fabsf(wv.y)), fmaxf(fabsf(wv.z), fabsf(wv.w)));
#pragma unroll
    for (int msk = 1; msk < 64; msk <<= 1) m4 = fmaxf(m4, __shfl_xor(m4, msk));
    if (lane == 0) red[w] = m4;
    __syncthreads();
    float t = fmaxf(fmaxf(fmaxf(red[0], red[1]), fmaxf(red[2], red[3])), 1e-8f);
    float vv[4] = {wv.x, wv.y, wv.z, wv.w};
    int c = tx * 4;
    ushort4 qh, ql;
    us* ph = (us*)&qh; us* pl = (us*)&ql;
#pragma unroll
    for (int j = 0; j < 4; ++j) {
        float s = fmaxf(__uint_as_float(smax[c + j]), 1e-8f);
        float sh = bf2f(f2bf(s));
        float rho = (s - sh) / sh;
        float q = logq_exact(vv[j], t);
        float wp = q + q * rho;
        split2(wp, ph[j], pl[j]);
    }
    *(ushort4*)(wh + (size_t)n * KP + c) = qh;
    *(ushort4*)(wl + (size_t)n * KP + c) = ql;
    if (tx < 64) {
        us h = 0, l = 0;
        if (tx < 32) { int r = tx & 15; split2(lB[(size_t)r * Nn + n], h, l); }
        else if (tx == 32) split2(bias[n], h, l);
        wh[(size_t)n * KP + 1024 + tx] = h;
        wl[(size_t)n * KP + 1024 + tx] = l;
    }
}

// ---------------- GEMM: C = Ah @ (W'h + W'l)^T via 2 MFMA passes, 2-phase dbuf pipeline ----------------
// MODE 0: linear f32 C[M][Nn].  MODE 1: qkv epilogue — q plane f32 (C), v plane f32 (vbuf),
//         k plane split bf16 -> Khg/Klg [bh][s][64].

template <int MODE>
__global__ __launch_bounds__(256) void k_gemm(const us* __restrict__ Aq_,
                                              const us* __restrict__ Bh_, const us* __restrict__ Bl_,
                                              float* __restrict__ C, int Nn,
                                              us* __restrict__ Khg, us* __restrict__ Klg,
                                              float* __restrict__ vbuf) {
    __shared__ us LA[2][4096], LBh[2][4096], LBl[2][4096];   // [128][32] each, 48KB total
    int tid = threadIdx.x;
    int bm = blockIdx.x, bn = blockIdx.y;
    int lane = tid & 63, w = tid >> 6;
    int wm = w >> 1, wn = w & 1;
    int l15 = lane & 15, l4 = lane >> 4;
    const us* aP  = Aq_ + (size_t)(bm * 128 + (tid >> 2)) * KP + (tid & 3) * 8;
    const us* bhP = Bh_ + (size_t)(bn * 128 + (tid >> 2)) * KP + (tid & 3) * 8;
    const us* blP = Bl_ + (size_t)(bn * 128 + (tid >> 2)) * KP + (tid & 3) * 8;
    f32x4 zero4 = {0.f, 0.f, 0.f, 0.f};
    f32x4 acc[4][4];
#pragma unroll
    for (int i = 0; i < 4; ++i)
#pragma unroll
        for (int j = 0; j < 4; ++j) acc[i][j] = zero4;

#define GSTAGE(buf, kt)                                            \
    do {                                                           \
        int k0_ = (kt) * 32;                                       \
        gll16(aP + k0_,  &LA[(buf)][0] + tid * 8);                 \
        gll16(aP + (size_t)64 * KP + k0_,  &LA[(buf)][2048] + tid * 8);  \
        gll16(bhP + k0_, &LBh[(buf)][0] + tid * 8);                \
        gll16(bhP + (size_t)64 * KP + k0_, &LBh[(buf)][2048] + tid * 8); \
        gll16(blP + k0_, &LBl[(buf)][0] + tid * 8);                \
        gll16(blP + (size_t)64 * KP + k0_, &LBl[(buf)][2048] + tid * 8); \
    } while (0)

    GSTAGE(0, 0);
    __syncthreads();
    int cur = 0;
    for (int kt = 0; kt < NT; ++kt) {
        if (kt + 1 < NT) GSTAGE(cur ^ 1, kt + 1);
        bf16x8 ah[4], bh[4], bl[4];
#pragma unroll
        for (int i = 0; i < 4; ++i) {
            int ro = (wm * 64 + i * 16 + l15) * 32 + l4 * 8;
            int co = (wn * 64 + i * 16 + l15) * 32 + l4 * 8;
            ah[i] = *(const bf16x8*)(&LA[cur][0] + ro);
            bh[i] = *(const bf16x8*)(&LBh[cur][0] + co);
            bl[i] = *(const bf16x8*)(&LBl[cur][0] + co);
        }
#pragma unroll
        for (int mi = 0; mi < 4; ++mi)
#pragma unroll
            for (int ni = 0; ni < 4; ++ni) {
                acc[mi][ni] = __builtin_amdgcn_mfma_f32_16x16x32_bf16(ah[mi], bh[ni], acc[mi][ni], 0, 0, 0);
                acc[mi][ni] = __builtin_amdgcn_mfma_f32_16x16x32_bf16(ah[mi], bl[ni], acc[mi][ni], 0, 0, 0);
            }
        __syncthreads();
        cur ^= 1;
    }
#undef GSTAGE

    int plane = bn >> 3;   // MODE 1 only; block-uniform
#pragma unroll
    for (int mi = 0; mi < 4; ++mi) {
#pragma unroll
        for (int ni = 0; ni < 4; ++ni) {
            int ncol = bn * 128 + wn * 64 + ni * 16 + l15;
            size_t mbase = (size_t)bm * 128 + wm * 64 + mi * 16 + l4 * 4;
#pragma unroll
            for (int rr = 0; rr < 4; ++rr) {
                float v = acc[mi][ni][rr];
                size_t m = mbase + rr;
                if (MODE == 0) {
                    C[m * (size_t)Nn + ncol] = v;
                } else {
                    int cc = ncol & 1023;
                    if (plane == 0) {
                        C[m * DD + cc] = v;
                    } else if (plane == 2) {
                        vbuf[m * DD + cc] = v;
                    } else {
                        us hh, ll; split2(v, hh, ll);
                        size_t d = ((size_t)((m >> 11) * 16 + (cc >> 6)) * SS + (m & 2047)) * 64 + (cc & 63);
                        Khg[d] = hh; Klg[d] = ll;
                    }
                }
            }
        }
    }
}

// ---------------- V transpose+split: vbuf f32 -> vth/vtl [bh][hd][s-permuted] bf16 ----------------

__global__ __launch_bounds__(256) void k_transpose_v(const float* __restrict__ vbuf,
                                                     us* __restrict__ vth, us* __restrict__ vtl) {
    __shared__ us th[64][72], tl[64][72];
    int st = blockIdx.x, bh = blockIdx.y;
    int bb = bh >> 4, h = bh & 15;
    int s0 = st * 64, tid = threadIdx.x;
    int sl = tid >> 2, c0 = (tid & 3) * 16;
    const float* src = vbuf + (size_t)(bb * SS + s0 + sl) * DD + h * 64 + c0;
#pragma unroll
    for (int j4 = 0; j4 < 4; ++j4) {
        float4 v = *(const float4*)(src + j4 * 4);
        float vv[4] = {v.x, v.y, v.z, v.w};
#pragma unroll
        for (int j = 0; j < 4; ++j) {
            us hh, ll; split2(vv[j], hh, ll);
            th[c0 + j4 * 4 + j][sl] = hh;
            tl[c0 + j4 * 4 + j][sl] = ll;
        }
    }
    __syncthreads();
#pragma unroll
    for (int p = 0; p < 2; ++p) {
        int gidx = p * 256 + tid;
        int hd = gidx >> 3, g = gidx & 7;
        int base = (g >> 2) * 32 + (g & 3) * 4;
        ushort4 a, b2, c, d2;
        a.x = th[hd][base];      a.y = th[hd][base + 1];  a.z = th[hd][base + 2];  a.w = th[hd][base + 3];
        b2.x = th[hd][base + 16]; b2.y = th[hd][base + 17]; b2.z = th[hd][base + 18]; b2.w = th[hd][base + 19];
        c.x = tl[hd][base];      c.y = tl[hd][base + 1];  c.z = tl[hd][base + 2];  c.w = tl[hd][base + 3];
        d2.x = tl[hd][base + 16]; d2.y = tl[hd][base + 17]; d2.z = tl[hd][base + 18]; d2.w = tl[hd][base + 19];
        size_t dof = ((size_t)bh * 64 + hd) * SS + s0 + g * 8;
        *(ushort4*)(vth + dof) = a;  *(ushort4*)(vth + dof + 4) = b2;
        *(ushort4*)(vtl + dof) = c;  *(ushort4*)(vtl + dof + 4) = d2;
    }
}

// ---------------- causal flash attention, hi/lo split Q,K,V,P; TK=64, double-buffered ----------------
// output written IN-PLACE into the q plane (each block touches only its own rows x cols)

#define SCL 0.18033688011112042f   /* 0.125 * log2(e) */

__global__ __launch_bounds__(256, 2) void k_attn(float* qo,
                                                 const us* __restrict__ Khg, const us* __restrict__ Klg,
                                                 const us* __restrict__ vth, const us* __restrict__ vtl) {
    __shared__ us L[2][16384];  // per buf: [0]=Kh [4096]=Kl [8192]=Vh [12288]=Vl, 64x64 bf16, XOR-8 swz
    int bh = blockIdx.x;
    int qt = (int)(gridDim.y - 1) - blockIdx.y;   // heavy q-tiles first
    int b = bh >> 4, h = bh & 15;
    int q0 = qt * 128;
    int tid = threadIdx.x, w = tid >> 6, lane = tid & 63;
    int l15 = lane & 15, l4 = lane >> 4;
    int qw = q0 + w * 32;
    int swz = l15 & 7;

    bf16x8 qh[2][2], ql[2][2];
#pragma unroll
    for (int qb = 0; qb < 2; ++qb)
#pragma unroll
        for (int hf = 0; hf < 2; ++hf) {
            const float* qp = qo + (size_t)(b * SS + qw + qb * 16 + l15) * DD + h * 64 + hf * 32 + l4 * 8;
            float4 a = *(const float4*)qp;
            float4 c = *(const float4*)(qp + 4);
            float vv[8] = {a.x, a.y, a.z, a.w, c.x, c.y, c.z, c.w};
            bf16x8 hq, lq;
#pragma unroll
            for (int j = 0; j < 8; ++j) {
                us hh = f2bf(vv[j]);
                hq[j] = (short)hh;
                lq[j] = (short)f2bf(vv[j] - bf2f(hh));
            }
            qh[qb][hf] = hq; ql[qb][hf] = lq;
        }

    f32x4 zero4 = {0.f, 0.f, 0.f, 0.f};
    f32x4 of[2][4];
#pragma unroll
    for (int i = 0; i < 2; ++i)
#pragma unroll
        for (int j = 0; j < 4; ++j) of[i][j] = zero4;
    float mrow[2] = {-1e30f, -1e30f}, lrow[2] = {0.f, 0.f};

    int r0 = tid >> 3, sl0 = (tid & 7) ^ (r0 & 7);
    int g1 = tid + 256, r1 = g1 >> 3, sl1 = (g1 & 7) ^ (r1 & 7);
    int koff0 = (bh * SS + r0) * 64 + sl0 * 8;
    int koff1 = (bh * SS + r1) * 64 + sl1 * 8;
    int voff0 = (bh * 64 + r0) * SS + sl0 * 8;
    int voff1 = (bh * 64 + r1) * SS + sl1 * 8;

    int ntiles = qt * 2 + 2;

#define STAGE(buf, tt)                                           \
    do {                                                         \
        int kv_ = (tt) * 64;                                     \
        us* D_ = &L[(buf)][0];                                   \
        int kadd_ = kv_ << 6;                                    \
        gll16(Khg + koff0 + kadd_, D_ + tid * 8);                \
        gll16(Khg + koff1 + kadd_, D_ + 2048 + tid * 8);         \
        gll16(Klg + koff0 + kadd_, D_ + 4096 + tid * 8);         \
        gll16(Klg + koff1 + kadd_, D_ + 6144 + tid * 8);         \
        gll16(vth + voff0 + kv_, D_ + 8192 + tid * 8);           \
        gll16(vth + voff1 + kv_, D_ + 10240 + tid * 8);          \
        gll16(vtl + voff0 + kv_, D_ + 12288 + tid * 8);          \
        gll16(vtl + voff1 + kv_, D_ + 14336 + tid * 8);          \
    } while (0)

    STAGE(0, 0);
    __syncthreads();
    int cur = 0;

    for (int t = 0; t < ntiles; ++t) {
        int kv0 = t * 64;
        if (t + 1 < ntiles) STAGE(cur ^ 1, t + 1);

        if (kv0 <= qw + 31) {
            const us* Lc = &L[cur][0];

            f32x4 sf[4][2];
#pragma unroll
            for (int i = 0; i < 4; ++i) { sf[i][0] = zero4; sf[i][1] = zero4; }
            __builtin_amdgcn_s_setprio(1);
#pragma unroll
            for (int kb = 0; kb < 4; ++kb) {
                int rbase = (kb * 16 + l15) * 64;
#pragma unroll
                for (int hf = 0; hf < 2; ++hf) {
                    int off = rbase + (((hf * 4 + l4) ^ swz) * 8);
                    bf16x8 kh = *(const bf16x8*)(Lc + off);
                    bf16x8 kl = *(const bf16x8*)(Lc + 4096 + off);
#pragma unroll
                    for (int qb = 0; qb < 2; ++qb) {
                        sf[kb][qb] = __builtin_amdgcn_mfma_f32_16x16x32_bf16(kh, qh[qb][hf], sf[kb][qb], 0, 0, 0);
                        sf[kb][qb] = __builtin_amdgcn_mfma_f32_16x16x32_bf16(kh, ql[qb][hf], sf[kb][qb], 0, 0, 0);
                        sf[kb][qb] = __builtin_amdgcn_mfma_f32_16x16x32_bf16(kl, qh[qb][hf], sf[kb][qb], 0, 0, 0);
                    }
                }
            }
            __builtin_amdgcn_s_setprio(0);

            bool diag = (kv0 + 63 > qw);   // wave-uniform
            u32x4 PH[2][2], PL[2][2];
#pragma unroll
            for (int qb = 0; qb < 2; ++qb) {
                float pv[16];
                if (diag) {
                    int qg = qw + qb * 16 + l15;
#pragma unroll
                    for (int kb = 0; kb < 4; ++kb)
#pragma unroll
                        for (int rr = 0; rr < 4; ++rr) {
                            int kvg = kv0 + kb * 16 + l4 * 4 + rr;
                            float sc = sf[kb][qb][rr] * SCL;
                            pv[kb * 4 + rr] = (kvg > qg) ? -1e30f : sc;
                        }
                } else {
#pragma unroll
                    for (int kb = 0; kb < 4; ++kb)
#pragma unroll
                        for (int rr = 0; rr < 4; ++rr)
                            pv[kb * 4 + rr] = sf[kb][qb][rr] * SCL;
                }
                float tmax = pv[0];
#pragma unroll
                for (int i = 1; i < 16; ++i) tmax = fmaxf(tmax, pv[i]);
                tmax = fmaxf(tmax, __shfl_xor(tmax, 16));
                tmax = fmaxf(tmax, __shfl_xor(tmax, 32));
                float mnew = fmaxf(mrow[qb], tmax);
                float fac = __builtin_amdgcn_exp2f(mrow[qb] - mnew);
                mrow[qb] = mnew;
                float ps = 0.f;
#pragma unroll
                for (int i = 0; i < 16; ++i) {
                    pv[i] = __builtin_amdgcn_exp2f(pv[i] - mnew);
                    ps += pv[i];
                }
                ps += __shfl_xor(ps, 16); ps += __shfl_xor(ps, 32);
                lrow[qb] = lrow[qb] * fac + ps;
#pragma unroll
                for (int ks = 0; ks < 2; ++ks)
#pragma unroll
                    for (int c2 = 0; c2 < 4; ++c2) {
                        float p0 = pv[ks * 8 + c2 * 2], p1 = pv[ks * 8 + c2 * 2 + 1];
                        unsigned u = cvtpk(p0, p1);
                        float h0 = __uint_as_float(u << 16);
                        float h1 = __uint_as_float(u & 0xffff0000u);
                        unsigned ul = cvtpk(p0 - h0, p1 - h1);
                        PH[qb][ks][c2] = u; PL[qb][ks][c2] = ul;
                    }
                float fr0 = __shfl(fac, l4 * 4 + 0);
                float fr1 = __shfl(fac, l4 * 4 + 1);
                float fr2 = __shfl(fac, l4 * 4 + 2);
                float fr3 = __shfl(fac, l4 * 4 + 3);
#pragma unroll
                for (int hb = 0; hb < 4; ++hb) {
                    of[qb][hb][0] *= fr0; of[qb][hb][1] *= fr1;
                    of[qb][hb][2] *= fr2; of[qb][hb][3] *= fr3;
                }
            }

            __builtin_amdgcn_s_setprio(1);
#pragma unroll
            for (int hb = 0; hb < 4; ++hb) {
                int rbase = (hb * 16 + l15) * 64;
#pragma unroll
                for (int ks = 0; ks < 2; ++ks) {
                    int off = rbase + (((ks * 4 + l4) ^ swz) * 8);
                    bf16x8 vh = *(const bf16x8*)(Lc + 8192 + off);
                    bf16x8 vl = *(const bf16x8*)(Lc + 12288 + off);
#pragma unroll
                    for (int qb = 0; qb < 2; ++qb) {
                        bf16x8 pa = (bf16x8)PH[qb][ks];
                        bf16x8 pb = (bf16x8)PL[qb][ks];
                        of[qb][hb] = __builtin_amdgcn_mfma_f32_16x16x32_bf16(pa, vh, of[qb][hb], 0, 0, 0);
                        of[qb][hb] = __builtin_amdgcn_mfma_f32_16x16x32_bf16(pa, vl, of[qb][hb], 0, 0, 0);
                        of[qb][hb] = __builtin_amdgcn_mfma_f32_16x16x32_bf16(pb, vh, of[qb][hb], 0, 0, 0);
                    }
                }
            }
            __builtin_amdgcn_s_setprio(0);
        }

        __syncthreads();
        cur ^= 1;
    }
#undef STAGE

#pragma unroll
    for (int qb = 0; qb < 2; ++qb) {
        float linv = 1.f / lrow[qb];
        float f0 = __shfl(linv, l4 * 4 + 0);
        float f1 = __shfl(linv, l4 * 4 + 1);
        float f2 = __shfl(linv, l4 * 4 + 2);
        float f3 = __shfl(linv, l4 * 4 + 3);
        int qgb = qw + qb * 16 + l4 * 4;
#pragma unroll
        for (int hb = 0; hb < 4; ++hb) {
            int col = h * 64 + hb * 16 + l15;
            qo[((size_t)(b * SS + qgb + 0)) * DD + col] = of[qb][hb][0] * f0;
            qo[((size_t)(b * SS + qgb + 1)) * DD + col] = of[qb][hb][1] * f1;
            qo[((size_t)(b * SS + qgb + 2)) * DD + col] = of[qb][hb][2] * f2;
            qo[((size_t)(b * SS + qgb + 3)) * DD + col] = of[qb][hb][3] * f3;
        }
    }
}

// ---------------- launcher ----------------

extern "C" void kernel_launch(void* const* d_in, const int* in_sizes, int n_in,
                              void* d_out, int out_size, void* d_ws, size_t ws_size,
                              hipStream_t stream) {
    const float* hidden  = (const float*)d_in[0];
    const float* W_attn  = (const float*)d_in[2];
    const float* b_attn  = (const float*)d_in[3];
    const float* lA_attn = (const float*)d_in[4];
    const float* lB_attn = (const float*)d_in[5];
    const float* W_proj  = (const float*)d_in[6];
    const float* b_proj  = (const float*)d_in[7];
    const float* lA_proj = (const float*)d_in[8];
    const float* lB_proj = (const float*)d_in[9];
    float* out = (float*)d_out;

    char* ws = (char*)d_ws;
    unsigned* s1 = (unsigned*)(ws);
    unsigned* s2 = (unsigned*)(ws + 4096);
    us* xq  = (us*)(ws + 8192);                              // 17,825,792 B (8192x1088x2)
    us* vth = xq;                                            // overlay (phase B: xq dead)
    us* wh1 = (us*)(ws + 8192 + 17825792);                   // 6,684,672
    us* wl1 = (us*)(ws + 8192 + 17825792 + 6684672);         // 6,684,672
    us* wh2 = (us*)(ws + 8192 + 17825792 + 2 * 6684672);     // 2,228,224
    us* wl2 = (us*)(ws + 8192 + 17825792 + 2 * 6684672 + 2228224);
    char* pbase = ws + 8192 + 17825792 + 2 * 6684672 + 2 * 2228224;
    float* qbuf = (float*)pbase;                             // 33,554,432 (q plane; attn out in-place)
    float* vbuf = (float*)(pbase + 33554432);                // 33,554,432 (v plane, dead after transpose)
    us* Khg = (us*)(pbase + 2 * (size_t)33554432);           // 16,777,216
    us* Klg = (us*)(pbase + 2 * (size_t)33554432 + 16777216);
    us* vtl = (us*)(pbase + 2 * (size_t)33554432 + 2 * (size_t)16777216);  // 16,777,216

    k_zero<<<8, 256, 0, stream>>>(s1, 2048);

    // ---- qkv projection ----
    k_colmax<<<dim3(4, 64), 256, 0, stream>>>(hidden, s1);
    k_quant_rows<<<MTOT, 256, 0, stream>>>(hidden, s1, xq);
    k_lora_x<<<MTOT / 4, 256, 0, stream>>>(hidden, lA_attn, xq);
    k_quant_w<<<3072, 256, 0, stream>>>(W_attn, lB_attn, b_attn, s1, wh1, wl1, 3072);
    k_gemm<1><<<dim3(64, 24), 256, 0, stream>>>(xq, wh1, wl1, qbuf, DQKV, Khg, Klg, vbuf);

    // ---- attention (output in-place into qbuf) ----
    k_transpose_v<<<dim3(32, 64), 256, 0, stream>>>(vbuf, vth, vtl);
    k_attn<<<dim3(64, 16), 256, 0, stream>>>(qbuf, Khg, Klg, vth, vtl);

    // ---- output projection ----
    k_colmax<<<dim3(4, 64), 256, 0, stream>>>(qbuf, s2);
    k_quant_rows<<<MTOT, 256, 0, stream>>>(qbuf, s2, xq);
    k_lora_x<<<MTOT / 4, 256, 0, stream>>>(qbuf, lA_proj, xq);
    k_quant_w<<<1024, 256, 0, stream>>>(W_proj, lB_proj, b_proj, s2, wh2, wl2, 1024);
    k_gemm<0><<<dim3(64, 8), 256, 0, stream>>>(xq, wh2, wl2, out, DD, nullptr, nullptr, nullptr);
}

// Round 6
// 498.998 us; speedup vs baseline: 1.3911x; 1.0651x over previous
//
#include <hip/hip_runtime.h>

#define SS 2048
#define DD 1024
#define DQKV 3072
#define KP 1088            // 1024 + 16 lora-hi + 16 lora-lo + 1 bias + 31 pad
#define NT (KP / 32)       // 34 K-steps
#define MTOT 8192
#define QKSZ ((size_t)MTOT * DD)   // floats per q/k/v plane

typedef unsigned short us;
typedef __attribute__((ext_vector_type(8))) short bf16x8;
typedef __attribute__((ext_vector_type(4))) float f32x4;
typedef __attribute__((ext_vector_type(4))) unsigned u32x4;

#define WAITVM(N) asm volatile("s_waitcnt vmcnt(" #N ")" ::: "memory")

__device__ __forceinline__ us f2bf(float f) {
    unsigned u = __float_as_uint(f);
    return (us)((u + 0x7fffu + ((u >> 16) & 1u)) >> 16);
}
__device__ __forceinline__ float bf2f(us h) { return __uint_as_float(((unsigned)h) << 16); }
__device__ __forceinline__ void split2(float q, us& h, us& l) {
    h = f2bf(q); l = f2bf(q - bf2f(h));
}
__device__ __forceinline__ unsigned cvtpk(float lo, float hi) {
    unsigned r;
    asm("v_cvt_pk_bf16_f32 %0, %1, %2" : "=v"(r) : "v"(lo), "v"(hi));
    return r;
}

// exact log-domain fake quant level: e = round(log2(clip(|x|/s, 2^-255, 1))), boundary in double
__device__ __forceinline__ int logq_e(float ax, float s) {
    int e = 0;
    if (ax < s) {
        double r = (double)ax / (double)s;
        int ex;
        double mant = frexp(r, &ex);                   // [0.5,1)
        e = (mant >= 0.70710678118654752440) ? ex : ex - 1;
        e = (e < -255) ? -255 : e;
    }
    return e;
}
__device__ __forceinline__ float logq_exact(float x, float s) {
    float ax = fabsf(x);
    if (ax == 0.f) return copysignf(0.f, x);
    return copysignf(ldexpf(s, logq_e(ax, s)), x);
}

__device__ __forceinline__ void gll16(const void* g, void* l) {
    __builtin_amdgcn_global_load_lds(
        (const __attribute__((address_space(1))) void*)g,
        (__attribute__((address_space(3))) void*)l, 16, 0, 0);
}

// ---------------- scales / quant / lora prep ----------------

__global__ void k_zero(unsigned* p, int n) {
    int i = blockIdx.x * 256 + threadIdx.x;
    if (i < n) p[i] = 0u;
}

__global__ void k_colmax(const float* __restrict__ x, unsigned* __restrict__ smax) {
    int c = blockIdx.x * 256 + threadIdx.x;
    int r0 = blockIdx.y * 128;
    float m = 0.f;
    for (int r = 0; r < 128; ++r) m = fmaxf(m, fabsf(x[(size_t)(r0 + r) * DD + c]));
    atomicMax(smax + c, __float_as_uint(m));
}

// quantize row -> EXACT bf16 rep Ah = sign * bf16(s) * 2^e  (xq = Ah*(1+rho_c) exactly)
__global__ void k_quant_rows(const float* __restrict__ x, const unsigned* __restrict__ smax,
                             us* __restrict__ xq) {
    int m = blockIdx.x, tx = threadIdx.x;
    float4 xv = ((const float4*)(x + (size_t)m * DD))[tx];
    int c = tx * 4;
    float vv[4] = {xv.x, xv.y, xv.z, xv.w};
    ushort4 qh;
    us* ph = (us*)&qh;
#pragma unroll
    for (int j = 0; j < 4; ++j) {
        float s = fmaxf(__uint_as_float(smax[c + j]), 1e-8f);
        float sh = bf2f(f2bf(s));
        float ax = fabsf(vv[j]);
        if (ax == 0.f) ph[j] = (us)((__float_as_uint(vv[j]) >> 16) & 0x8000u);
        else ph[j] = f2bf(copysignf(ldexpf(sh, logq_e(ax, s)), vv[j]));
    }
    *(ushort4*)(xq + (size_t)m * KP + c) = qh;
    if (tx == 0) xq[(size_t)m * KP + 1056] = 0x3F80;          // bias col = 1.0
    else if (tx < 32) xq[(size_t)m * KP + 1056 + tx] = 0;     // pad 1057..1087
}

// lora cols: 1024+r = hi(2*x@lA), 1040+r = lo  (exact pair vs duplicated lB cols)
__global__ void k_lora_x(const float* __restrict__ x, const float* __restrict__ lA,
                         us* __restrict__ xq) {
    int w = threadIdx.x >> 6, lane = threadIdx.x & 63;
    int m = blockIdx.x * 4 + w;
    const float* xr = x + (size_t)m * DD;
    float acc[16];
#pragma unroll
    for (int r = 0; r < 16; ++r) acc[r] = 0.f;
#pragma unroll
    for (int i = 0; i < 4; ++i) {
        int c0 = i * 256 + lane * 4;
        float4 xv = *(const float4*)(xr + c0);
        float xs4[4] = {xv.x, xv.y, xv.z, xv.w};
#pragma unroll
        for (int j = 0; j < 4; ++j) {
            float xs = xs4[j];
            const float4* lr = (const float4*)(lA + (size_t)(c0 + j) * 16);
            float4 a0 = lr[0], a1 = lr[1], a2 = lr[2], a3 = lr[3];
            acc[0] += xs * a0.x; acc[1] += xs * a0.y; acc[2] += xs * a0.z; acc[3] += xs * a0.w;
            acc[4] += xs * a1.x; acc[5] += xs * a1.y; acc[6] += xs * a1.z; acc[7] += xs * a1.w;
            acc[8] += xs * a2.x; acc[9] += xs * a2.y; acc[10] += xs * a2.z; acc[11] += xs * a2.w;
            acc[12] += xs * a3.x; acc[13] += xs * a3.y; acc[14] += xs * a3.z; acc[15] += xs * a3.w;
        }
    }
#pragma unroll
    for (int msk = 1; msk < 64; msk <<= 1)
#pragma unroll
        for (int r = 0; r < 16; ++r) acc[r] += __shfl_xor(acc[r], msk);
    if (lane == 0) {
#pragma unroll
        for (int r = 0; r < 16; ++r) {
            us h, l; split2(2.0f * acc[r], h, l);
            xq[(size_t)m * KP + 1024 + r] = h;
            xq[(size_t)m * KP + 1040 + r] = l;
        }
    }
}

// weight quant + fold activation-scale residual: W' = Wq*(1+rho_c); split hi/lo.
__global__ __launch_bounds__(256) void k_quant_w(const float* __restrict__ W, const float* __restrict__ lB,
                                                 const float* __restrict__ bias,
                                                 const unsigned* __restrict__ smax,
                                                 us* __restrict__ wh, us* __restrict__ wl, int Nn) {
    __shared__ float red[4];
    int n = blockIdx.x, tx = threadIdx.x;
    int lane = tx & 63, w = tx >> 6;
    float4 wv = ((const float4*)(W + (size_t)n * DD))[tx];
    float m4 = fmaxf(fmaxf(fabsf(wv.x), fabsf(wv.y)), fmaxf(fabsf(wv.z), fabsf(wv.w)));
#pragma unroll
    for (int msk = 1; msk < 64; msk <<= 1) m4 = fmaxf(m4, __shfl_xor(m4, msk));
    if (lane == 0) red[w] = m4;
    __syncthreads();
    float t = fmaxf(fmaxf(fmaxf(red[0], red[1]), fmaxf(red[2], red[3])), 1e-8f);
    float vv[4] = {wv.x, wv.y, wv.z, wv.w};
    int c = tx * 4;
    ushort4 qh, ql;
    us* ph = (us*)&qh; us* pl = (us*)&ql;
#pragma unroll
    for (int j = 0; j < 4; ++j) {
        float s = fmaxf(__uint_as_float(smax[c + j]), 1e-8f);
        float sh = bf2f(f2bf(s));
        float rho = (s - sh) / sh;
        float q = logq_exact(vv[j], t);
        float wp = q + q * rho;
        split2(wp, ph[j], pl[j]);
    }
    *(ushort4*)(wh + (size_t)n * KP + c) = qh;
    *(ushort4*)(wl + (size_t)n * KP + c) = ql;
    if (tx < 64) {
        us h = 0, l = 0;
        if (tx < 32) { int r = tx & 15; split2(lB[(size_t)r * Nn + n], h, l); }
        else if (tx == 32) split2(bias[n], h, l);
        wh[(size_t)n * KP + 1024 + tx] = h;
        wl[(size_t)n * KP + 1024 + tx] = l;
    }
}

// ---------------- GEMM: C = Ah @ (W'h + W'l)^T, 2 MFMA passes ----------------
// counted-vmcnt 3-tile pipeline; LDS granule XOR-swizzle (g ^= (row>>1)&3) both-sides.
// MODE 0: linear f32 C[M][Nn].  MODE 1: qkv epilogue — q f32, v f32, k split bf16 [bh][s][64].

template <int MODE>
__global__ __launch_bounds__(256) void k_gemm(const us* __restrict__ Aq_,
                                              const us* __restrict__ Bh_, const us* __restrict__ Bl_,
                                              float* __restrict__ C, int Nn,
                                              us* __restrict__ Khg, us* __restrict__ Klg,
                                              float* __restrict__ vbuf) {
    __shared__ us LA[2][4096], LBh[2][4096], LBl[2][4096];   // [128][32] each, 48KB total
    int tid = threadIdx.x;
    int bm = blockIdx.x, bn = blockIdx.y;
    int lane = tid & 63, w = tid >> 6;
    int wm = w >> 1, wn = w & 1;
    int l15 = lane & 15, l4 = lane >> 4;
    // staging: row r=tid>>2, source granule pre-swizzled: g' = (tid&3) ^ ((r>>1)&3)
    int gsrc = ((tid & 3) ^ ((tid >> 3) & 3)) * 8;
    const us* aP  = Aq_ + (size_t)(bm * 128 + (tid >> 2)) * KP + gsrc;
    const us* bhP = Bh_ + (size_t)(bn * 128 + (tid >> 2)) * KP + gsrc;
    const us* blP = Bl_ + (size_t)(bn * 128 + (tid >> 2)) * KP + gsrc;
    f32x4 zero4 = {0.f, 0.f, 0.f, 0.f};
    f32x4 acc[4][4];
#pragma unroll
    for (int i = 0; i < 4; ++i)
#pragma unroll
        for (int j = 0; j < 4; ++j) acc[i][j] = zero4;

#define GSTAGE(buf, kt)                                            \
    do {                                                           \
        int k0_ = (kt) * 32;                                       \
        gll16(aP + k0_,  &LA[(buf)][0] + tid * 8);                 \
        gll16(aP + (size_t)64 * KP + k0_,  &LA[(buf)][2048] + tid * 8);  \
        gll16(bhP + k0_, &LBh[(buf)][0] + tid * 8);                \
        gll16(bhP + (size_t)64 * KP + k0_, &LBh[(buf)][2048] + tid * 8); \
        gll16(blP + k0_, &LBl[(buf)][0] + tid * 8);                \
        gll16(blP + (size_t)64 * KP + k0_, &LBl[(buf)][2048] + tid * 8); \
    } while (0)

    GSTAGE(0, 0);
    GSTAGE(1, 1);
    int cur = 0;
    // read-side swizzle: row R = wm*64+i*16+l15 -> (R>>1)&3 == (l15>>1)&3 (base mult of 16)
    int gsw = (l4 ^ ((l15 >> 1) & 3)) * 8;
    for (int kt = 0; kt < NT; ++kt) {
        if (kt + 1 < NT) WAITVM(6); else WAITVM(0);
        __builtin_amdgcn_s_barrier();
        bf16x8 ah[4], bh[4], bl[4];
#pragma unroll
        for (int i = 0; i < 4; ++i) {
            int ro = (wm * 64 + i * 16 + l15) * 32 + gsw;
            int co = (wn * 64 + i * 16 + l15) * 32 + gsw;
            ah[i] = *(const bf16x8*)(&LA[cur][0] + ro);
            bh[i] = *(const bf16x8*)(&LBh[cur][0] + co);
            bl[i] = *(const bf16x8*)(&LBl[cur][0] + co);
        }
#pragma unroll
        for (int mi = 0; mi < 4; ++mi)
#pragma unroll
            for (int ni = 0; ni < 4; ++ni) {
                acc[mi][ni] = __builtin_amdgcn_mfma_f32_16x16x32_bf16(ah[mi], bh[ni], acc[mi][ni], 0, 0, 0);
                acc[mi][ni] = __builtin_amdgcn_mfma_f32_16x16x32_bf16(ah[mi], bl[ni], acc[mi][ni], 0, 0, 0);
            }
        __builtin_amdgcn_s_barrier();
        if (kt + 2 < NT) GSTAGE(cur, kt + 2);
        cur ^= 1;
    }
#undef GSTAGE

    int plane = bn >> 3;   // MODE 1 only; block-uniform
#pragma unroll
    for (int mi = 0; mi < 4; ++mi) {
#pragma unroll
        for (int ni = 0; ni < 4; ++ni) {
            int ncol = bn * 128 + wn * 64 + ni * 16 + l15;
            size_t mbase = (size_t)bm * 128 + wm * 64 + mi * 16 + l4 * 4;
#pragma unroll
            for (int rr = 0; rr < 4; ++rr) {
                float v = acc[mi][ni][rr];
                size_t m = mbase + rr;
                if (MODE == 0) {
                    C[m * (size_t)Nn + ncol] = v;
                } else {
                    int cc = ncol & 1023;
                    if (plane == 0) {
                        C[m * DD + cc] = v;
                    } else if (plane == 2) {
                        vbuf[m * DD + cc] = v;
                    } else {
                        us hh, ll; split2(v, hh, ll);
                        size_t d = ((size_t)((m >> 11) * 16 + (cc >> 6)) * SS + (m & 2047)) * 64 + (cc & 63);
                        Khg[d] = hh; Klg[d] = ll;
                    }
                }
            }
        }
    }
}

// ---------------- V transpose+split: vbuf f32 -> vth/vtl [bh][hd][s-permuted] bf16 ----------------

__global__ __launch_bounds__(256) void k_transpose_v(const float* __restrict__ vbuf,
                                                     us* __restrict__ vth, us* __restrict__ vtl) {
    __shared__ us th[64][72], tl[64][72];
    int st = blockIdx.x, bh = blockIdx.y;
    int bb = bh >> 4, h = bh & 15;
    int s0 = st * 64, tid = threadIdx.x;
    int sl = tid >> 2, c0 = (tid & 3) * 16;
    const float* src = vbuf + (size_t)(bb * SS + s0 + sl) * DD + h * 64 + c0;
#pragma unroll
    for (int j4 = 0; j4 < 4; ++j4) {
        float4 v = *(const float4*)(src + j4 * 4);
        float vv[4] = {v.x, v.y, v.z, v.w};
#pragma unroll
        for (int j = 0; j < 4; ++j) {
            us hh, ll; split2(vv[j], hh, ll);
            th[c0 + j4 * 4 + j][sl] = hh;
            tl[c0 + j4 * 4 + j][sl] = ll;
        }
    }
    __syncthreads();
#pragma unroll
    for (int p = 0; p < 2; ++p) {
        int gidx = p * 256 + tid;
        int hd = gidx >> 3, g = gidx & 7;
        int base = (g >> 2) * 32 + (g & 3) * 4;
        ushort4 a, b2, c, d2;
        a.x = th[hd][base];      a.y = th[hd][base + 1];  a.z = th[hd][base + 2];  a.w = th[hd][base + 3];
        b2.x = th[hd][base + 16]; b2.y = th[hd][base + 17]; b2.z = th[hd][base + 18]; b2.w = th[hd][base + 19];
        c.x = tl[hd][base];      c.y = tl[hd][base + 1];  c.z = tl[hd][base + 2];  c.w = tl[hd][base + 3];
        d2.x = tl[hd][base + 16]; d2.y = tl[hd][base + 17]; d2.z = tl[hd][base + 18]; d2.w = tl[hd][base + 19];
        size_t dof = ((size_t)bh * 64 + hd) * SS + s0 + g * 8;
        *(ushort4*)(vth + dof) = a;  *(ushort4*)(vth + dof + 4) = b2;
        *(ushort4*)(vtl + dof) = c;  *(ushort4*)(vtl + dof + 4) = d2;
    }
}

// ---------------- causal flash attention; counted-vmcnt 3-tile pipeline ----------------
// output written IN-PLACE into the q plane

#define SCL 0.18033688011112042f   /* 0.125 * log2(e) */

__global__ __launch_bounds__(256, 2) void k_attn(float* qo,
                                                 const us* __restrict__ Khg, const us* __restrict__ Klg,
                                                 const us* __restrict__ vth, const us* __restrict__ vtl) {
    __shared__ us L[2][16384];  // per buf: [0]=Kh [4096]=Kl [8192]=Vh [12288]=Vl, 64x64 bf16, XOR-8 swz
    int bh = blockIdx.x;
    int qt = (int)(gridDim.y - 1) - blockIdx.y;   // heavy q-tiles first
    int b = bh >> 4, h = bh & 15;
    int q0 = qt * 128;
    int tid = threadIdx.x, w = tid >> 6, lane = tid & 63;
    int l15 = lane & 15, l4 = lane >> 4;
    int qw = q0 + w * 32;
    int swz = l15 & 7;

    bf16x8 qh[2][2], ql[2][2];
#pragma unroll
    for (int qb = 0; qb < 2; ++qb)
#pragma unroll
        for (int hf = 0; hf < 2; ++hf) {
            const float* qp = qo + (size_t)(b * SS + qw + qb * 16 + l15) * DD + h * 64 + hf * 32 + l4 * 8;
            float4 a = *(const float4*)qp;
            float4 c = *(const float4*)(qp + 4);
            float vv[8] = {a.x, a.y, a.z, a.w, c.x, c.y, c.z, c.w};
            bf16x8 hq, lq;
#pragma unroll
            for (int j = 0; j < 8; ++j) {
                us hh = f2bf(vv[j]);
                hq[j] = (short)hh;
                lq[j] = (short)f2bf(vv[j] - bf2f(hh));
            }
            qh[qb][hf] = hq; ql[qb][hf] = lq;
        }

    f32x4 zero4 = {0.f, 0.f, 0.f, 0.f};
    f32x4 of[2][4];
#pragma unroll
    for (int i = 0; i < 2; ++i)
#pragma unroll
        for (int j = 0; j < 4; ++j) of[i][j] = zero4;
    float mrow[2] = {-1e30f, -1e30f}, lrow[2] = {0.f, 0.f};

    int r0 = tid >> 3, sl0 = (tid & 7) ^ (r0 & 7);
    int g1 = tid + 256, r1 = g1 >> 3, sl1 = (g1 & 7) ^ (r1 & 7);
    int koff0 = (bh * SS + r0) * 64 + sl0 * 8;
    int koff1 = (bh * SS + r1) * 64 + sl1 * 8;
    int voff0 = (bh * 64 + r0) * SS + sl0 * 8;
    int voff1 = (bh * 64 + r1) * SS + sl1 * 8;

    int ntiles = qt * 2 + 2;

#define STAGE(buf, tt)                                           \
    do {                                                         \
        int kv_ = (tt) * 64;                                     \
        us* D_ = &L[(buf)][0];                                   \
        int kadd_ = kv_ << 6;                                    \
        gll16(Khg + koff0 + kadd_, D_ + tid * 8);                \
        gll16(Khg + koff1 + kadd_, D_ + 2048 + tid * 8);         \
        gll16(Klg + koff0 + kadd_, D_ + 4096 + tid * 8);         \
        gll16(Klg + koff1 + kadd_, D_ + 6144 + tid * 8);         \
        gll16(vth + voff0 + kv_, D_ + 8192 + tid * 8);           \
        gll16(vth + voff1 + kv_, D_ + 10240 + tid * 8);          \
        gll16(vtl + voff0 + kv_, D_ + 12288 + tid * 8);          \
        gll16(vtl + voff1 + kv_, D_ + 14336 + tid * 8);          \
    } while (0)

    STAGE(0, 0);
    STAGE(1, 1);
    int cur = 0;

    for (int t = 0; t < ntiles; ++t) {
        int kv0 = t * 64;
        if (t + 1 < ntiles) WAITVM(8); else WAITVM(0);
        __builtin_amdgcn_s_barrier();

        if (kv0 <= qw + 31) {
            const us* Lc = &L[cur][0];

            f32x4 sf[4][2];
#pragma unroll
            for (int i = 0; i < 4; ++i) { sf[i][0] = zero4; sf[i][1] = zero4; }
            __builtin_amdgcn_s_setprio(1);
#pragma unroll
            for (int kb = 0; kb < 4; ++kb) {
                int rbase = (kb * 16 + l15) * 64;
#pragma unroll
                for (int hf = 0; hf < 2; ++hf) {
                    int off = rbase + (((hf * 4 + l4) ^ swz) * 8);
                    bf16x8 kh = *(const bf16x8*)(Lc + off);
                    bf16x8 kl = *(const bf16x8*)(Lc + 4096 + off);
#pragma unroll
                    for (int qb = 0; qb < 2; ++qb) {
                        sf[kb][qb] = __builtin_amdgcn_mfma_f32_16x16x32_bf16(kh, qh[qb][hf], sf[kb][qb], 0, 0, 0);
                        sf[kb][qb] = __builtin_amdgcn_mfma_f32_16x16x32_bf16(kh, ql[qb][hf], sf[kb][qb], 0, 0, 0);
                        sf[kb][qb] = __builtin_amdgcn_mfma_f32_16x16x32_bf16(kl, qh[qb][hf], sf[kb][qb], 0, 0, 0);
                    }
                }
            }
            __builtin_amdgcn_s_setprio(0);

            bool diag = (kv0 + 63 > qw);   // wave-uniform
            u32x4 PH[2][2], PL[2][2];
#pragma unroll
            for (int qb = 0; qb < 2; ++qb) {
                float pv[16];
                if (diag) {
                    int qg = qw + qb * 16 + l15;
#pragma unroll
                    for (int kb = 0; kb < 4; ++kb)
#pragma unroll
                        for (int rr = 0; rr < 4; ++rr) {
                            int kvg = kv0 + kb * 16 + l4 * 4 + rr;
                            float sc = sf[kb][qb][rr] * SCL;
                            pv[kb * 4 + rr] = (kvg > qg) ? -1e30f : sc;
                        }
                } else {
#pragma unroll
                    for (int kb = 0; kb < 4; ++kb)
#pragma unroll
                        for (int rr = 0; rr < 4; ++rr)
                            pv[kb * 4 + rr] = sf[kb][qb][rr] * SCL;
                }
                float tmax = pv[0];
#pragma unroll
                for (int i = 1; i < 16; ++i) tmax = fmaxf(tmax, pv[i]);
                tmax = fmaxf(tmax, __shfl_xor(tmax, 16));
                tmax = fmaxf(tmax, __shfl_xor(tmax, 32));
                float mnew = fmaxf(mrow[qb], tmax);
                float fac = __builtin_amdgcn_exp2f(mrow[qb] - mnew);
                mrow[qb] = mnew;
                float ps = 0.f;
#pragma unroll
                for (int i = 0; i < 16; ++i) {
                    pv[i] = __builtin_amdgcn_exp2f(pv[i] - mnew);
                    ps += pv[i];
                }
                ps += __shfl_xor(ps, 16); ps += __shfl_xor(ps, 32);
                lrow[qb] = lrow[qb] * fac + ps;
#pragma unroll
                for (int ks = 0; ks < 2; ++ks)
#pragma unroll
                    for (int c2 = 0; c2 < 4; ++c2) {
                        float p0 = pv[ks * 8 + c2 * 2], p1 = pv[ks * 8 + c2 * 2 + 1];
                        unsigned u = cvtpk(p0, p1);
                        float h0 = __uint_as_float(u << 16);
                        float h1 = __uint_as_float(u & 0xffff0000u);
                        unsigned ul = cvtpk(p0 - h0, p1 - h1);
                        PH[qb][ks][c2] = u; PL[qb][ks][c2] = ul;
                    }
                float fr0 = __shfl(fac, l4 * 4 + 0);
                float fr1 = __shfl(fac, l4 * 4 + 1);
                float fr2 = __shfl(fac, l4 * 4 + 2);
                float fr3 = __shfl(fac, l4 * 4 + 3);
#pragma unroll
                for (int hb = 0; hb < 4; ++hb) {
                    of[qb][hb][0] *= fr0; of[qb][hb][1] *= fr1;
                    of[qb][hb][2] *= fr2; of[qb][hb][3] *= fr3;
                }
            }

            __builtin_amdgcn_s_setprio(1);
#pragma unroll
            for (int hb = 0; hb < 4; ++hb) {
                int rbase = (hb * 16 + l15) * 64;
#pragma unroll
                for (int ks = 0; ks < 2; ++ks) {
                    int off = rbase + (((ks * 4 + l4) ^ swz) * 8);
                    bf16x8 vh = *(const bf16x8*)(Lc + 8192 + off);
                    bf16x8 vl = *(const bf16x8*)(Lc + 12288 + off);
#pragma unroll
                    for (int qb = 0; qb < 2; ++qb) {
                        bf16x8 pa = (bf16x8)PH[qb][ks];
                        bf16x8 pb = (bf16x8)PL[qb][ks];
                        of[qb][hb] = __builtin_amdgcn_mfma_f32_16x16x32_bf16(pa, vh, of[qb][hb], 0, 0, 0);
                        of[qb][hb] = __builtin_amdgcn_mfma_f32_16x16x32_bf16(pa, vl, of[qb][hb], 0, 0, 0);
                        of[qb][hb] = __builtin_amdgcn_mfma_f32_16x16x32_bf16(pb, vh, of[qb][hb], 0, 0, 0);
                    }
                }
            }
            __builtin_amdgcn_s_setprio(0);
        }

        __builtin_amdgcn_s_barrier();
        if (t + 2 < ntiles) STAGE(cur, t + 2);
        cur ^= 1;
    }
#undef STAGE

#pragma unroll
    for (int qb = 0; qb < 2; ++qb) {
        float linv = 1.f / lrow[qb];
        float f0 = __shfl(linv, l4 * 4 + 0);
        float f1 = __shfl(linv, l4 * 4 + 1);
        float f2 = __shfl(linv, l4 * 4 + 2);
        float f3 = __shfl(linv, l4 * 4 + 3);
        int qgb = qw + qb * 16 + l4 * 4;
#pragma unroll
        for (int hb = 0; hb < 4; ++hb) {
            int col = h * 64 + hb * 16 + l15;
            qo[((size_t)(b * SS + qgb + 0)) * DD + col] = of[qb][hb][0] * f0;
            qo[((size_t)(b * SS + qgb + 1)) * DD + col] = of[qb][hb][1] * f1;
            qo[((size_t)(b * SS + qgb + 2)) * DD + col] = of[qb][hb][2] * f2;
            qo[((size_t)(b * SS + qgb + 3)) * DD + col] = of[qb][hb][3] * f3;
        }
    }
}

// ---------------- launcher ----------------

extern "C" void kernel_launch(void* const* d_in, const int* in_sizes, int n_in,
                              void* d_out, int out_size, void* d_ws, size_t ws_size,
                              hipStream_t stream) {
    const float* hidden  = (const float*)d_in[0];
    const float* W_attn  = (const float*)d_in[2];
    const float* b_attn  = (const float*)d_in[3];
    const float* lA_attn = (const float*)d_in[4];
    const float* lB_attn = (const float*)d_in[5];
    const float* W_proj  = (const float*)d_in[6];
    const float* b_proj  = (const float*)d_in[7];
    const float* lA_proj = (const float*)d_in[8];
    const float* lB_proj = (const float*)d_in[9];
    float* out = (float*)d_out;

    char* ws = (char*)d_ws;
    unsigned* s1 = (unsigned*)(ws);
    unsigned* s2 = (unsigned*)(ws + 4096);
    us* xq  = (us*)(ws + 8192);                              // 17,825,792 B (8192x1088x2)
    us* vth = xq;                                            // overlay (phase B: xq dead)
    us* wh1 = (us*)(ws + 8192 + 17825792);                   // 6,684,672
    us* wl1 = (us*)(ws + 8192 + 17825792 + 6684672);         // 6,684,672
    us* wh2 = (us*)(ws + 8192 + 17825792 + 2 * 6684672);     // 2,228,224
    us* wl2 = (us*)(ws + 8192 + 17825792 + 2 * 6684672 + 2228224);
    char* pbase = ws + 8192 + 17825792 + 2 * 6684672 + 2 * 2228224;
    float* qbuf = (float*)pbase;                             // 33,554,432 (q plane; attn out in-place)
    float* vbuf = (float*)(pbase + 33554432);                // 33,554,432 (v plane, dead after transpose)
    us* Khg = (us*)(pbase + 2 * (size_t)33554432);           // 16,777,216
    us* Klg = (us*)(pbase + 2 * (size_t)33554432 + 16777216);
    us* vtl = (us*)(pbase + 2 * (size_t)33554432 + 2 * (size_t)16777216);  // 16,777,216

    k_zero<<<8, 256, 0, stream>>>(s1, 2048);

    // ---- qkv projection ----
    k_colmax<<<dim3(4, 64), 256, 0, stream>>>(hidden, s1);
    k_quant_rows<<<MTOT, 256, 0, stream>>>(hidden, s1, xq);
    k_lora_x<<<MTOT / 4, 256, 0, stream>>>(hidden, lA_attn, xq);
    k_quant_w<<<3072, 256, 0, stream>>>(W_attn, lB_attn, b_attn, s1, wh1, wl1, 3072);
    k_gemm<1><<<dim3(64, 24), 256, 0, stream>>>(xq, wh1, wl1, qbuf, DQKV, Khg, Klg, vbuf);

    // ---- attention (output in-place into qbuf) ----
    k_transpose_v<<<dim3(32, 64), 256, 0, stream>>>(vbuf, vth, vtl);
    k_attn<<<dim3(64, 16), 256, 0, stream>>>(qbuf, Khg, Klg, vth, vtl);

    // ---- output projection ----
    k_colmax<<<dim3(4, 64), 256, 0, stream>>>(qbuf, s2);
    k_quant_rows<<<MTOT, 256, 0, stream>>>(qbuf, s2, xq);
    k_lora_x<<<MTOT / 4, 256, 0, stream>>>(qbuf, lA_proj, xq);
    k_quant_w<<<1024, 256, 0, stream>>>(W_proj, lB_proj, b_proj, s2, wh2, wl2, 1024);
    k_gemm<0><<<dim3(64, 8), 256, 0, stream>>>(xq, wh2, wl2, out, DD, nullptr, nullptr, nullptr);
}

// Round 7
// 473.103 us; speedup vs baseline: 1.4673x; 1.0547x over previous
//
#include <hip/hip_runtime.h>

#define SS 2048
#define DD 1024
#define DQKV 3072
#define KP 1088            // 1024 + 16 lora-hi + 16 lora-lo + 1 bias + 31 pad
#define NT64 17            // K-tiles of 64
#define MTOT 8192
#define QKSZ ((size_t)MTOT * DD)   // floats per q/k/v plane

typedef unsigned short us;
typedef __attribute__((ext_vector_type(8))) short bf16x8;
typedef __attribute__((ext_vector_type(4))) float f32x4;
typedef __attribute__((ext_vector_type(4))) unsigned u32x4;

#define WAITVM(N) asm volatile("s_waitcnt vmcnt(" #N ")" ::: "memory")
#define WAITLGKM0 asm volatile("s_waitcnt lgkmcnt(0)" ::: "memory")

__device__ __forceinline__ us f2bf(float f) {
    unsigned u = __float_as_uint(f);
    return (us)((u + 0x7fffu + ((u >> 16) & 1u)) >> 16);
}
__device__ __forceinline__ float bf2f(us h) { return __uint_as_float(((unsigned)h) << 16); }
__device__ __forceinline__ void split2(float q, us& h, us& l) {
    h = f2bf(q); l = f2bf(q - bf2f(h));
}
__device__ __forceinline__ unsigned cvtpk(float lo, float hi) {
    unsigned r;
    asm("v_cvt_pk_bf16_f32 %0, %1, %2" : "=v"(r) : "v"(lo), "v"(hi));
    return r;
}

// exact log-domain fake quant level: e = round(log2(clip(|x|/s, 2^-255, 1))), boundary in double
__device__ __forceinline__ int logq_e(float ax, float s) {
    int e = 0;
    if (ax < s) {
        double r = (double)ax / (double)s;
        int ex;
        double mant = frexp(r, &ex);                   // [0.5,1)
        e = (mant >= 0.70710678118654752440) ? ex : ex - 1;
        e = (e < -255) ? -255 : e;
    }
    return e;
}
__device__ __forceinline__ float logq_exact(float x, float s) {
    float ax = fabsf(x);
    if (ax == 0.f) return copysignf(0.f, x);
    return copysignf(ldexpf(s, logq_e(ax, s)), x);
}

__device__ __forceinline__ void gll16(const void* g, void* l) {
    __builtin_amdgcn_global_load_lds(
        (const __attribute__((address_space(1))) void*)g,
        (__attribute__((address_space(3))) void*)l, 16, 0, 0);
}

// ---------------- scales / quant / lora prep ----------------

__global__ void k_zero(unsigned* p, int n) {
    int i = blockIdx.x * 256 + threadIdx.x;
    if (i < n) p[i] = 0u;
}

__global__ void k_colmax(const float* __restrict__ x, unsigned* __restrict__ smax) {
    int c = blockIdx.x * 256 + threadIdx.x;
    int r0 = blockIdx.y * 128;
    float m = 0.f;
    for (int r = 0; r < 128; ++r) m = fmaxf(m, fabsf(x[(size_t)(r0 + r) * DD + c]));
    atomicMax(smax + c, __float_as_uint(m));
}

// quantize row -> EXACT bf16 rep Ah = sign * bf16(s) * 2^e  (xq = Ah*(1+rho_c) exactly)
__global__ void k_quant_rows(const float* __restrict__ x, const unsigned* __restrict__ smax,
                             us* __restrict__ xq) {
    int m = blockIdx.x, tx = threadIdx.x;
    float4 xv = ((const float4*)(x + (size_t)m * DD))[tx];
    int c = tx * 4;
    float vv[4] = {xv.x, xv.y, xv.z, xv.w};
    ushort4 qh;
    us* ph = (us*)&qh;
#pragma unroll
    for (int j = 0; j < 4; ++j) {
        float s = fmaxf(__uint_as_float(smax[c + j]), 1e-8f);
        float sh = bf2f(f2bf(s));
        float ax = fabsf(vv[j]);
        if (ax == 0.f) ph[j] = (us)((__float_as_uint(vv[j]) >> 16) & 0x8000u);
        else ph[j] = f2bf(copysignf(ldexpf(sh, logq_e(ax, s)), vv[j]));
    }
    *(ushort4*)(xq + (size_t)m * KP + c) = qh;
    if (tx == 0) xq[(size_t)m * KP + 1056] = 0x3F80;          // bias col = 1.0
    else if (tx < 32) xq[(size_t)m * KP + 1056 + tx] = 0;     // pad 1057..1087
}

// lora cols: 1024+r = hi(2*x@lA), 1040+r = lo  (exact pair vs duplicated lB cols)
__global__ void k_lora_x(const float* __restrict__ x, const float* __restrict__ lA,
                         us* __restrict__ xq) {
    int w = threadIdx.x >> 6, lane = threadIdx.x & 63;
    int m = blockIdx.x * 4 + w;
    const float* xr = x + (size_t)m * DD;
    float acc[16];
#pragma unroll
    for (int r = 0; r < 16; ++r) acc[r] = 0.f;
#pragma unroll
    for (int i = 0; i < 4; ++i) {
        int c0 = i * 256 + lane * 4;
        float4 xv = *(const float4*)(xr + c0);
        float xs4[4] = {xv.x, xv.y, xv.z, xv.w};
#pragma unroll
        for (int j = 0; j < 4; ++j) {
            float xs = xs4[j];
            const float4* lr = (const float4*)(lA + (size_t)(c0 + j) * 16);
            float4 a0 = lr[0], a1 = lr[1], a2 = lr[2], a3 = lr[3];
            acc[0] += xs * a0.x; acc[1] += xs * a0.y; acc[2] += xs * a0.z; acc[3] += xs * a0.w;
            acc[4] += xs * a1.x; acc[5] += xs * a1.y; acc[6] += xs * a1.z; acc[7] += xs * a1.w;
            acc[8] += xs * a2.x; acc[9] += xs * a2.y; acc[10] += xs * a2.z; acc[11] += xs * a2.w;
            acc[12] += xs * a3.x; acc[13] += xs * a3.y; acc[14] += xs * a3.z; acc[15] += xs * a3.w;
        }
    }
#pragma unroll
    for (int msk = 1; msk < 64; msk <<= 1)
#pragma unroll
        for (int r = 0; r < 16; ++r) acc[r] += __shfl_xor(acc[r], msk);
    if (lane == 0) {
#pragma unroll
        for (int r = 0; r < 16; ++r) {
            us h, l; split2(2.0f * acc[r], h, l);
            xq[(size_t)m * KP + 1024 + r] = h;
            xq[(size_t)m * KP + 1040 + r] = l;
        }
    }
}

// weight quant + fold activation-scale residual: W' = Wq*(1+rho_c); split hi/lo.
__global__ __launch_bounds__(256) void k_quant_w(const float* __restrict__ W, const float* __restrict__ lB,
                                                 const float* __restrict__ bias,
                                                 const unsigned* __restrict__ smax,
                                                 us* __restrict__ wh, us* __restrict__ wl, int Nn) {
    __shared__ float red[4];
    int n = blockIdx.x, tx = threadIdx.x;
    int lane = tx & 63, w = tx >> 6;
    float4 wv = ((const float4*)(W + (size_t)n * DD))[tx];
    float m4 = fmaxf(fmaxf(fabsf(wv.x), fabsf(wv.y)), fmaxf(fabsf(wv.z), fabsf(wv.w)));
#pragma unroll
    for (int msk = 1; msk < 64; msk <<= 1) m4 = fmaxf(m4, __shfl_xor(m4, msk));
    if (lane == 0) red[w] = m4;
    __syncthreads();
    float t = fmaxf(fmaxf(fmaxf(red[0], red[1]), fmaxf(red[2], red[3])), 1e-8f);
    float vv[4] = {wv.x, wv.y, wv.z, wv.w};
    int c = tx * 4;
    ushort4 qh, ql;
    us* ph = (us*)&qh; us* pl = (us*)&ql;
#pragma unroll
    for (int j = 0; j < 4; ++j) {
        float s = fmaxf(__uint_as_float(smax[c + j]), 1e-8f);
        float sh = bf2f(f2bf(s));
        float rho = (s - sh) / sh;
        float q = logq_exact(vv[j], t);
        float wp = q + q * rho;
        split2(wp, ph[j], pl[j]);
    }
    *(ushort4*)(wh + (size_t)n * KP + c) = qh;
    *(ushort4*)(wl + (size_t)n * KP + c) = ql;
    if (tx < 64) {
        us h = 0, l = 0;
        if (tx < 32) { int r = tx & 15; split2(lB[(size_t)r * Nn + n], h, l); }
        else if (tx == 32) split2(bias[n], h, l);
        wh[(size_t)n * KP + 1024 + tx] = h;
        wl[(size_t)n * KP + 1024 + tx] = l;
    }
}

// ---------------- GEMM: C = Ah @ (W'h + W'l)^T, 2 MFMA passes ----------------
// 8-wave (512t) BM=256 BN=128 BK=64; 2 sub-phases per K-tile; counted vmcnt(8);
// STAGE(t+2) overlapped with ksub1 MFMA; XOR-granule swizzle (g ^= row&7) both-sides.
// MODE 0: linear f32 C[M][Nn].  MODE 1: qkv epilogue — q f32, v f32, k split bf16 [bh][s][64].

template <int MODE>
__global__ __launch_bounds__(512, 2) void k_gemm(const us* __restrict__ Aq_,
                                                 const us* __restrict__ Bh_, const us* __restrict__ Bl_,
                                                 float* __restrict__ C, int Nn,
                                                 us* __restrict__ Khg, us* __restrict__ Klg,
                                                 float* __restrict__ vbuf) {
    __shared__ us LA[2][16384];    // A 256x64 bf16 per buf (64KB total)
    __shared__ us LBh[2][8192];    // Bh 128x64 (32KB)
    __shared__ us LBl[2][8192];    // Bl 128x64 (32KB)
    int tid = threadIdx.x;
    int bm = blockIdx.x, bn = blockIdx.y;
    int lane = tid & 63, w = tid >> 6;
    int wm = w >> 2, wn = w & 3;             // 2 x 4 wave grid; per-wave out 128x32
    int l15 = lane & 15, l4 = lane >> 4;
    // staging: thread covers row srow(+64*i), dest granule tid&7; source pre-swizzled
    int srow = tid >> 3;
    int gsrc = ((tid & 7) ^ (srow & 7)) * 8;
    const us* aP  = Aq_ + (size_t)(bm * 256 + srow) * KP + gsrc;
    const us* bhP = Bh_ + (size_t)(bn * 128 + srow) * KP + gsrc;
    const us* blP = Bl_ + (size_t)(bn * 128 + srow) * KP + gsrc;
    f32x4 zero4 = {0.f, 0.f, 0.f, 0.f};
    f32x4 acc[8][2];
#pragma unroll
    for (int i = 0; i < 8; ++i) { acc[i][0] = zero4; acc[i][1] = zero4; }

#define GSTAGE(buf, kt)                                               \
    do {                                                              \
        int k0_ = (kt) * 64;                                          \
        gll16(aP + k0_,                    &LA[(buf)][0]     + tid * 8); \
        gll16(aP + (size_t)64  * KP + k0_, &LA[(buf)][4096]  + tid * 8); \
        gll16(aP + (size_t)128 * KP + k0_, &LA[(buf)][8192]  + tid * 8); \
        gll16(aP + (size_t)192 * KP + k0_, &LA[(buf)][12288] + tid * 8); \
        gll16(bhP + k0_,                   &LBh[(buf)][0]    + tid * 8); \
        gll16(bhP + (size_t)64 * KP + k0_, &LBh[(buf)][4096] + tid * 8); \
        gll16(blP + k0_,                   &LBl[(buf)][0]    + tid * 8); \
        gll16(blP + (size_t)64 * KP + k0_, &LBl[(buf)][4096] + tid * 8); \
    } while (0)

    GSTAGE(0, 0);
    GSTAGE(1, 1);
    WAITVM(8);
    __builtin_amdgcn_s_barrier();
    __builtin_amdgcn_sched_barrier(0);

    int gsw0 = ((l4)     ^ (l15 & 7)) * 8;   // ksub0 granule (swizzled), elements
    int gsw1 = ((4 + l4) ^ (l15 & 7)) * 8;   // ksub1
    int cur = 0;
    for (int kt = 0; kt < NT64; ++kt) {
        const us* A0  = &LA[cur][0];
        const us* Bh0 = &LBh[cur][0];
        const us* Bl0 = &LBl[cur][0];
        // ---- sub-phase 0 ----
        bf16x8 a0[8], b0h[2], b0l[2];
#pragma unroll
        for (int i = 0; i < 8; ++i)
            a0[i] = *(const bf16x8*)(A0 + (wm * 128 + i * 16 + l15) * 64 + gsw0);
#pragma unroll
        for (int i = 0; i < 2; ++i) {
            b0h[i] = *(const bf16x8*)(Bh0 + (wn * 32 + i * 16 + l15) * 64 + gsw0);
            b0l[i] = *(const bf16x8*)(Bl0 + (wn * 32 + i * 16 + l15) * 64 + gsw0);
        }
        __builtin_amdgcn_s_setprio(1);
#pragma unroll
        for (int mi = 0; mi < 8; ++mi)
#pragma unroll
            for (int ni = 0; ni < 2; ++ni) {
                acc[mi][ni] = __builtin_amdgcn_mfma_f32_16x16x32_bf16(a0[mi], b0h[ni], acc[mi][ni], 0, 0, 0);
                acc[mi][ni] = __builtin_amdgcn_mfma_f32_16x16x32_bf16(a0[mi], b0l[ni], acc[mi][ni], 0, 0, 0);
            }
        __builtin_amdgcn_s_setprio(0);
        // ---- sub-phase 1 reads ----
        bf16x8 a1[8], b1h[2], b1l[2];
#pragma unroll
        for (int i = 0; i < 8; ++i)
            a1[i] = *(const bf16x8*)(A0 + (wm * 128 + i * 16 + l15) * 64 + gsw1);
#pragma unroll
        for (int i = 0; i < 2; ++i) {
            b1h[i] = *(const bf16x8*)(Bh0 + (wn * 32 + i * 16 + l15) * 64 + gsw1);
            b1l[i] = *(const bf16x8*)(Bl0 + (wn * 32 + i * 16 + l15) * 64 + gsw1);
        }
        WAITLGKM0;                          // this wave done reading buf[cur]
        __builtin_amdgcn_sched_barrier(0);
        __builtin_amdgcn_s_barrier();       // all waves done reading buf[cur]
        __builtin_amdgcn_sched_barrier(0);
        if (kt + 2 < NT64) GSTAGE(cur, kt + 2);   // restage freed buffer; overlaps MFMA below
        __builtin_amdgcn_s_setprio(1);
#pragma unroll
        for (int mi = 0; mi < 8; ++mi)
#pragma unroll
            for (int ni = 0; ni < 2; ++ni) {
                acc[mi][ni] = __builtin_amdgcn_mfma_f32_16x16x32_bf16(a1[mi], b1h[ni], acc[mi][ni], 0, 0, 0);
                acc[mi][ni] = __builtin_amdgcn_mfma_f32_16x16x32_bf16(a1[mi], b1l[ni], acc[mi][ni], 0, 0, 0);
            }
        __builtin_amdgcn_s_setprio(0);
        if (kt + 2 < NT64) { WAITVM(8); } else { WAITVM(0); }   // tile kt+1 landed
        __builtin_amdgcn_s_barrier();
        __builtin_amdgcn_sched_barrier(0);
        cur ^= 1;
    }
#undef GSTAGE

    int plane = bn >> 3;   // MODE 1 only; block-uniform
#pragma unroll
    for (int mi = 0; mi < 8; ++mi) {
#pragma unroll
        for (int ni = 0; ni < 2; ++ni) {
            int ncol = bn * 128 + wn * 32 + ni * 16 + l15;
            size_t mbase = (size_t)bm * 256 + wm * 128 + mi * 16 + l4 * 4;
#pragma unroll
            for (int rr = 0; rr < 4; ++rr) {
                float v = acc[mi][ni][rr];
                size_t m = mbase + rr;
                if (MODE == 0) {
                    C[m * (size_t)Nn + ncol] = v;
                } else {
                    int cc = ncol & 1023;
                    if (plane == 0) {
                        C[m * DD + cc] = v;
                    } else if (plane == 2) {
                        vbuf[m * DD + cc] = v;
                    } else {
                        us hh, ll; split2(v, hh, ll);
                        size_t d = ((size_t)((m >> 11) * 16 + (cc >> 6)) * SS + (m & 2047)) * 64 + (cc & 63);
                        Khg[d] = hh; Klg[d] = ll;
                    }
                }
            }
        }
    }
}

// ---------------- V transpose+split: vbuf f32 -> vth/vtl [bh][hd][s-permuted] bf16 ----------------

__global__ __launch_bounds__(256) void k_transpose_v(const float* __restrict__ vbuf,
                                                     us* __restrict__ vth, us* __restrict__ vtl) {
    __shared__ us th[64][72], tl[64][72];
    int st = blockIdx.x, bh = blockIdx.y;
    int bb = bh >> 4, h = bh & 15;
    int s0 = st * 64, tid = threadIdx.x;
    int sl = tid >> 2, c0 = (tid & 3) * 16;
    const float* src = vbuf + (size_t)(bb * SS + s0 + sl) * DD + h * 64 + c0;
#pragma unroll
    for (int j4 = 0; j4 < 4; ++j4) {
        float4 v = *(const float4*)(src + j4 * 4);
        float vv[4] = {v.x, v.y, v.z, v.w};
#pragma unroll
        for (int j = 0; j < 4; ++j) {
            us hh, ll; split2(vv[j], hh, ll);
            th[c0 + j4 * 4 + j][sl] = hh;
            tl[c0 + j4 * 4 + j][sl] = ll;
        }
    }
    __syncthreads();
#pragma unroll
    for (int p = 0; p < 2; ++p) {
        int gidx = p * 256 + tid;
        int hd = gidx >> 3, g = gidx & 7;
        int base = (g >> 2) * 32 + (g & 3) * 4;
        ushort4 a, b2, c, d2;
        a.x = th[hd][base];      a.y = th[hd][base + 1];  a.z = th[hd][base + 2];  a.w = th[hd][base + 3];
        b2.x = th[hd][base + 16]; b2.y = th[hd][base + 17]; b2.z = th[hd][base + 18]; b2.w = th[hd][base + 19];
        c.x = tl[hd][base];      c.y = tl[hd][base + 1];  c.z = tl[hd][base + 2];  c.w = tl[hd][base + 3];
        d2.x = tl[hd][base + 16]; d2.y = tl[hd][base + 17]; d2.z = tl[hd][base + 18]; d2.w = tl[hd][base + 19];
        size_t dof = ((size_t)bh * 64 + hd) * SS + s0 + g * 8;
        *(ushort4*)(vth + dof) = a;  *(ushort4*)(vth + dof + 4) = b2;
        *(ushort4*)(vtl + dof) = c;  *(ushort4*)(vtl + dof + 4) = d2;
    }
}

// ---------------- causal flash attention; counted-vmcnt 3-tile pipeline ----------------
// output written IN-PLACE into the q plane

#define SCL 0.18033688011112042f   /* 0.125 * log2(e) */

__global__ __launch_bounds__(256, 2) void k_attn(float* qo,
                                                 const us* __restrict__ Khg, const us* __restrict__ Klg,
                                                 const us* __restrict__ vth, const us* __restrict__ vtl) {
    __shared__ us L[2][16384];  // per buf: [0]=Kh [4096]=Kl [8192]=Vh [12288]=Vl, 64x64 bf16, XOR-8 swz
    int bh = blockIdx.x;
    int qt = (int)(gridDim.y - 1) - blockIdx.y;   // heavy q-tiles first
    int b = bh >> 4, h = bh & 15;
    int q0 = qt * 128;
    int tid = threadIdx.x, w = tid >> 6, lane = tid & 63;
    int l15 = lane & 15, l4 = lane >> 4;
    int qw = q0 + w * 32;
    int swz = l15 & 7;

    bf16x8 qh[2][2], ql[2][2];
#pragma unroll
    for (int qb = 0; qb < 2; ++qb)
#pragma unroll
        for (int hf = 0; hf < 2; ++hf) {
            const float* qp = qo + (size_t)(b * SS + qw + qb * 16 + l15) * DD + h * 64 + hf * 32 + l4 * 8;
            float4 a = *(const float4*)qp;
            float4 c = *(const float4*)(qp + 4);
            float vv[8] = {a.x, a.y, a.z, a.w, c.x, c.y, c.z, c.w};
            bf16x8 hq, lq;
#pragma unroll
            for (int j = 0; j < 8; ++j) {
                us hh = f2bf(vv[j]);
                hq[j] = (short)hh;
                lq[j] = (short)f2bf(vv[j] - bf2f(hh));
            }
            qh[qb][hf] = hq; ql[qb][hf] = lq;
        }

    f32x4 zero4 = {0.f, 0.f, 0.f, 0.f};
    f32x4 of[2][4];
#pragma unroll
    for (int i = 0; i < 2; ++i)
#pragma unroll
        for (int j = 0; j < 4; ++j) of[i][j] = zero4;
    float mrow[2] = {-1e30f, -1e30f}, lrow[2] = {0.f, 0.f};

    int r0 = tid >> 3, sl0 = (tid & 7) ^ (r0 & 7);
    int g1 = tid + 256, r1 = g1 >> 3, sl1 = (g1 & 7) ^ (r1 & 7);
    int koff0 = (bh * SS + r0) * 64 + sl0 * 8;
    int koff1 = (bh * SS + r1) * 64 + sl1 * 8;
    int voff0 = (bh * 64 + r0) * SS + sl0 * 8;
    int voff1 = (bh * 64 + r1) * SS + sl1 * 8;

    int ntiles = qt * 2 + 2;

#define STAGE(buf, tt)                                           \
    do {                                                         \
        int kv_ = (tt) * 64;                                     \
        us* D_ = &L[(buf)][0];                                   \
        int kadd_ = kv_ << 6;                                    \
        gll16(Khg + koff0 + kadd_, D_ + tid * 8);                \
        gll16(Khg + koff1 + kadd_, D_ + 2048 + tid * 8);         \
        gll16(Klg + koff0 + kadd_, D_ + 4096 + tid * 8);         \
        gll16(Klg + koff1 + kadd_, D_ + 6144 + tid * 8);         \
        gll16(vth + voff0 + kv_, D_ + 8192 + tid * 8);           \
        gll16(vth + voff1 + kv_, D_ + 10240 + tid * 8);          \
        gll16(vtl + voff0 + kv_, D_ + 12288 + tid * 8);          \
        gll16(vtl + voff1 + kv_, D_ + 14336 + tid * 8);          \
    } while (0)

    STAGE(0, 0);
    STAGE(1, 1);
    int cur = 0;

    for (int t = 0; t < ntiles; ++t) {
        int kv0 = t * 64;
        if (t + 1 < ntiles) WAITVM(8); else WAITVM(0);
        __builtin_amdgcn_s_barrier();

        if (kv0 <= qw + 31) {
            const us* Lc = &L[cur][0];

            f32x4 sf[4][2];
#pragma unroll
            for (int i = 0; i < 4; ++i) { sf[i][0] = zero4; sf[i][1] = zero4; }
            __builtin_amdgcn_s_setprio(1);
#pragma unroll
            for (int kb = 0; kb < 4; ++kb) {
                int rbase = (kb * 16 + l15) * 64;
#pragma unroll
                for (int hf = 0; hf < 2; ++hf) {
                    int off = rbase + (((hf * 4 + l4) ^ swz) * 8);
                    bf16x8 kh = *(const bf16x8*)(Lc + off);
                    bf16x8 kl = *(const bf16x8*)(Lc + 4096 + off);
#pragma unroll
                    for (int qb = 0; qb < 2; ++qb) {
                        sf[kb][qb] = __builtin_amdgcn_mfma_f32_16x16x32_bf16(kh, qh[qb][hf], sf[kb][qb], 0, 0, 0);
                        sf[kb][qb] = __builtin_amdgcn_mfma_f32_16x16x32_bf16(kh, ql[qb][hf], sf[kb][qb], 0, 0, 0);
                        sf[kb][qb] = __builtin_amdgcn_mfma_f32_16x16x32_bf16(kl, qh[qb][hf], sf[kb][qb], 0, 0, 0);
                    }
                }
            }
            __builtin_amdgcn_s_setprio(0);

            bool diag = (kv0 + 63 > qw);   // wave-uniform
            u32x4 PH[2][2], PL[2][2];
#pragma unroll
            for (int qb = 0; qb < 2; ++qb) {
                float pv[16];
                if (diag) {
                    int qg = qw + qb * 16 + l15;
#pragma unroll
                    for (int kb = 0; kb < 4; ++kb)
#pragma unroll
                        for (int rr = 0; rr < 4; ++rr) {
                            int kvg = kv0 + kb * 16 + l4 * 4 + rr;
                            float sc = sf[kb][qb][rr] * SCL;
                            pv[kb * 4 + rr] = (kvg > qg) ? -1e30f : sc;
                        }
                } else {
#pragma unroll
                    for (int kb = 0; kb < 4; ++kb)
#pragma unroll
                        for (int rr = 0; rr < 4; ++rr)
                            pv[kb * 4 + rr] = sf[kb][qb][rr] * SCL;
                }
                float tmax = pv[0];
#pragma unroll
                for (int i = 1; i < 16; ++i) tmax = fmaxf(tmax, pv[i]);
                tmax = fmaxf(tmax, __shfl_xor(tmax, 16));
                tmax = fmaxf(tmax, __shfl_xor(tmax, 32));
                float mnew = fmaxf(mrow[qb], tmax);
                float fac = __builtin_amdgcn_exp2f(mrow[qb] - mnew);
                mrow[qb] = mnew;
                float ps = 0.f;
#pragma unroll
                for (int i = 0; i < 16; ++i) {
                    pv[i] = __builtin_amdgcn_exp2f(pv[i] - mnew);
                    ps += pv[i];
                }
                ps += __shfl_xor(ps, 16); ps += __shfl_xor(ps, 32);
                lrow[qb] = lrow[qb] * fac + ps;
#pragma unroll
                for (int ks = 0; ks < 2; ++ks)
#pragma unroll
                    for (int c2 = 0; c2 < 4; ++c2) {
                        float p0 = pv[ks * 8 + c2 * 2], p1 = pv[ks * 8 + c2 * 2 + 1];
                        unsigned u = cvtpk(p0, p1);
                        float h0 = __uint_as_float(u << 16);
                        float h1 = __uint_as_float(u & 0xffff0000u);
                        unsigned ul = cvtpk(p0 - h0, p1 - h1);
                        PH[qb][ks][c2] = u; PL[qb][ks][c2] = ul;
                    }
                float fr0 = __shfl(fac, l4 * 4 + 0);
                float fr1 = __shfl(fac, l4 * 4 + 1);
                float fr2 = __shfl(fac, l4 * 4 + 2);
                float fr3 = __shfl(fac, l4 * 4 + 3);
#pragma unroll
                for (int hb = 0; hb < 4; ++hb) {
                    of[qb][hb][0] *= fr0; of[qb][hb][1] *= fr1;
                    of[qb][hb][2] *= fr2; of[qb][hb][3] *= fr3;
                }
            }

            __builtin_amdgcn_s_setprio(1);
#pragma unroll
            for (int hb = 0; hb < 4; ++hb) {
                int rbase = (hb * 16 + l15) * 64;
#pragma unroll
                for (int ks = 0; ks < 2; ++ks) {
                    int off = rbase + (((ks * 4 + l4) ^ swz) * 8);
                    bf16x8 vh = *(const bf16x8*)(Lc + 8192 + off);
                    bf16x8 vl = *(const bf16x8*)(Lc + 12288 + off);
#pragma unroll
                    for (int qb = 0; qb < 2; ++qb) {
                        bf16x8 pa = (bf16x8)PH[qb][ks];
                        bf16x8 pb = (bf16x8)PL[qb][ks];
                        of[qb][hb] = __builtin_amdgcn_mfma_f32_16x16x32_bf16(pa, vh, of[qb][hb], 0, 0, 0);
                        of[qb][hb] = __builtin_amdgcn_mfma_f32_16x16x32_bf16(pa, vl, of[qb][hb], 0, 0, 0);
                        of[qb][hb] = __builtin_amdgcn_mfma_f32_16x16x32_bf16(pb, vh, of[qb][hb], 0, 0, 0);
                    }
                }
            }
            __builtin_amdgcn_s_setprio(0);
        }

        __builtin_amdgcn_s_barrier();
        if (t + 2 < ntiles) STAGE(cur, t + 2);
        cur ^= 1;
    }
#undef STAGE

#pragma unroll
    for (int qb = 0; qb < 2; ++qb) {
        float linv = 1.f / lrow[qb];
        float f0 = __shfl(linv, l4 * 4 + 0);
        float f1 = __shfl(linv, l4 * 4 + 1);
        float f2 = __shfl(linv, l4 * 4 + 2);
        float f3 = __shfl(linv, l4 * 4 + 3);
        int qgb = qw + qb * 16 + l4 * 4;
#pragma unroll
        for (int hb = 0; hb < 4; ++hb) {
            int col = h * 64 + hb * 16 + l15;
            qo[((size_t)(b * SS + qgb + 0)) * DD + col] = of[qb][hb][0] * f0;
            qo[((size_t)(b * SS + qgb + 1)) * DD + col] = of[qb][hb][1] * f1;
            qo[((size_t)(b * SS + qgb + 2)) * DD + col] = of[qb][hb][2] * f2;
            qo[((size_t)(b * SS + qgb + 3)) * DD + col] = of[qb][hb][3] * f3;
        }
    }
}

// ---------------- launcher ----------------

extern "C" void kernel_launch(void* const* d_in, const int* in_sizes, int n_in,
                              void* d_out, int out_size, void* d_ws, size_t ws_size,
                              hipStream_t stream) {
    const float* hidden  = (const float*)d_in[0];
    const float* W_attn  = (const float*)d_in[2];
    const float* b_attn  = (const float*)d_in[3];
    const float* lA_attn = (const float*)d_in[4];
    const float* lB_attn = (const float*)d_in[5];
    const float* W_proj  = (const float*)d_in[6];
    const float* b_proj  = (const float*)d_in[7];
    const float* lA_proj = (const float*)d_in[8];
    const float* lB_proj = (const float*)d_in[9];
    float* out = (float*)d_out;

    char* ws = (char*)d_ws;
    unsigned* s1 = (unsigned*)(ws);
    unsigned* s2 = (unsigned*)(ws + 4096);
    us* xq  = (us*)(ws + 8192);                              // 17,825,792 B (8192x1088x2)
    us* vth = xq;                                            // overlay (phase B: xq dead)
    us* wh1 = (us*)(ws + 8192 + 17825792);                   // 6,684,672
    us* wl1 = (us*)(ws + 8192 + 17825792 + 6684672);         // 6,684,672
    us* wh2 = (us*)(ws + 8192 + 17825792 + 2 * 6684672);     // 2,228,224
    us* wl2 = (us*)(ws + 8192 + 17825792 + 2 * 6684672 + 2228224);
    char* pbase = ws + 8192 + 17825792 + 2 * 6684672 + 2 * 2228224;
    float* qbuf = (float*)pbase;                             // 33,554,432 (q plane; attn out in-place)
    float* vbuf = (float*)(pbase + 33554432);                // 33,554,432 (v plane, dead after transpose)
    us* Khg = (us*)(pbase + 2 * (size_t)33554432);           // 16,777,216
    us* Klg = (us*)(pbase + 2 * (size_t)33554432 + 16777216);
    us* vtl = (us*)(pbase + 2 * (size_t)33554432 + 2 * (size_t)16777216);  // 16,777,216

    k_zero<<<8, 256, 0, stream>>>(s1, 2048);

    // ---- qkv projection ----
    k_colmax<<<dim3(4, 64), 256, 0, stream>>>(hidden, s1);
    k_quant_rows<<<MTOT, 256, 0, stream>>>(hidden, s1, xq);
    k_lora_x<<<MTOT / 4, 256, 0, stream>>>(hidden, lA_attn, xq);
    k_quant_w<<<3072, 256, 0, stream>>>(W_attn, lB_attn, b_attn, s1, wh1, wl1, 3072);
    k_gemm<1><<<dim3(32, 24), 512, 0, stream>>>(xq, wh1, wl1, qbuf, DQKV, Khg, Klg, vbuf);

    // ---- attention (output in-place into qbuf) ----
    k_transpose_v<<<dim3(32, 64), 256, 0, stream>>>(vbuf, vth, vtl);
    k_attn<<<dim3(64, 16), 256, 0, stream>>>(qbuf, Khg, Klg, vth, vtl);

    // ---- output projection ----
    k_colmax<<<dim3(4, 64), 256, 0, stream>>>(qbuf, s2);
    k_quant_rows<<<MTOT, 256, 0, stream>>>(qbuf, s2, xq);
    k_lora_x<<<MTOT / 4, 256, 0, stream>>>(qbuf, lA_proj, xq);
    k_quant_w<<<1024, 256, 0, stream>>>(W_proj, lB_proj, b_proj, s2, wh2, wl2, 1024);
    k_gemm<0><<<dim3(32, 8), 512, 0, stream>>>(xq, wh2, wl2, out, DD, nullptr, nullptr, nullptr);
}

// Round 8
// 450.730 us; speedup vs baseline: 1.5401x; 1.0496x over previous
//
#include <hip/hip_runtime.h>

#define SS 2048
#define DD 1024
#define DQKV 3072
#define KP 1088            // 1024 + 16 lora-hi + 16 lora-lo + 1 bias + 31 pad
#define NT64 17            // K-tiles of 64
#define MTOT 8192
#define QKSZ ((size_t)MTOT * DD)   // floats per q/k/v plane
#define SCL 0.18033688011112042f   /* 0.125 * log2(e), folded into K plane */

typedef unsigned short us;
typedef __attribute__((ext_vector_type(8))) short bf16x8;
typedef __attribute__((ext_vector_type(4))) float f32x4;
typedef __attribute__((ext_vector_type(4))) unsigned u32x4;

#define WAITVM(N) asm volatile("s_waitcnt vmcnt(" #N ")" ::: "memory")
#define WAITLGKM0 asm volatile("s_waitcnt lgkmcnt(0)" ::: "memory")

__device__ __forceinline__ us f2bf(float f) {
    unsigned u = __float_as_uint(f);
    return (us)((u + 0x7fffu + ((u >> 16) & 1u)) >> 16);
}
__device__ __forceinline__ float bf2f(us h) { return __uint_as_float(((unsigned)h) << 16); }
__device__ __forceinline__ void split2(float q, us& h, us& l) {
    h = f2bf(q); l = f2bf(q - bf2f(h));
}
__device__ __forceinline__ unsigned cvtpk(float lo, float hi) {
    unsigned r;
    asm("v_cvt_pk_bf16_f32 %0, %1, %2" : "=v"(r) : "v"(lo), "v"(hi));
    return r;
}

// exact log-domain fake quant level: e = round(log2(clip(|x|/s, 2^-255, 1))), boundary in double
__device__ __forceinline__ int logq_e(float ax, float s) {
    int e = 0;
    if (ax < s) {
        double r = (double)ax / (double)s;
        int ex;
        double mant = frexp(r, &ex);                   // [0.5,1)
        e = (mant >= 0.70710678118654752440) ? ex : ex - 1;
        e = (e < -255) ? -255 : e;
    }
    return e;
}
__device__ __forceinline__ float logq_exact(float x, float s) {
    float ax = fabsf(x);
    if (ax == 0.f) return copysignf(0.f, x);
    return copysignf(ldexpf(s, logq_e(ax, s)), x);
}

__device__ __forceinline__ void gll16(const void* g, void* l) {
    __builtin_amdgcn_global_load_lds(
        (const __attribute__((address_space(1))) void*)g,
        (__attribute__((address_space(3))) void*)l, 16, 0, 0);
}

// ---------------- scales / quant / lora prep ----------------

__global__ void k_zero(unsigned* p, int n) {
    int i = blockIdx.x * 256 + threadIdx.x;
    if (i < n) p[i] = 0u;
}

__global__ void k_colmax(const float* __restrict__ x, unsigned* __restrict__ smax) {
    int c = blockIdx.x * 256 + threadIdx.x;
    int r0 = blockIdx.y * 128;
    float m = 0.f;
    for (int r = 0; r < 128; ++r) m = fmaxf(m, fabsf(x[(size_t)(r0 + r) * DD + c]));
    atomicMax(smax + c, __float_as_uint(m));
}

// fused: quantize row (exact bf16 rep Ah) + lora cols + bias/pad; one pass over x
__global__ __launch_bounds__(256) void k_quant_lora(const float* __restrict__ x,
                                                    const unsigned* __restrict__ smax,
                                                    const float* __restrict__ lA,
                                                    us* __restrict__ xq) {
    __shared__ float red[4][16];
    int m = blockIdx.x, tx = threadIdx.x;
    int lane = tx & 63, w = tx >> 6;
    float4 xv = ((const float4*)(x + (size_t)m * DD))[tx];
    int c = tx * 4;
    float vv[4] = {xv.x, xv.y, xv.z, xv.w};
    ushort4 qh;
    us* ph = (us*)&qh;
#pragma unroll
    for (int j = 0; j < 4; ++j) {
        float s = fmaxf(__uint_as_float(smax[c + j]), 1e-8f);
        float sh = bf2f(f2bf(s));
        float ax = fabsf(vv[j]);
        if (ax == 0.f) ph[j] = (us)((__float_as_uint(vv[j]) >> 16) & 0x8000u);
        else ph[j] = f2bf(copysignf(ldexpf(sh, logq_e(ax, s)), vv[j]));
    }
    *(ushort4*)(xq + (size_t)m * KP + c) = qh;
    // lora partial: acc[r] = sum over this thread's 4 cols of x*lA
    float acc[16];
#pragma unroll
    for (int r = 0; r < 16; ++r) acc[r] = 0.f;
#pragma unroll
    for (int j = 0; j < 4; ++j) {
        float xs = vv[j];
        const float4* lr = (const float4*)(lA + (size_t)(c + j) * 16);
        float4 a0 = lr[0], a1 = lr[1], a2 = lr[2], a3 = lr[3];
        acc[0] += xs * a0.x; acc[1] += xs * a0.y; acc[2] += xs * a0.z; acc[3] += xs * a0.w;
        acc[4] += xs * a1.x; acc[5] += xs * a1.y; acc[6] += xs * a1.z; acc[7] += xs * a1.w;
        acc[8] += xs * a2.x; acc[9] += xs * a2.y; acc[10] += xs * a2.z; acc[11] += xs * a2.w;
        acc[12] += xs * a3.x; acc[13] += xs * a3.y; acc[14] += xs * a3.z; acc[15] += xs * a3.w;
    }
#pragma unroll
    for (int msk = 1; msk < 64; msk <<= 1)
#pragma unroll
        for (int r = 0; r < 16; ++r) acc[r] += __shfl_xor(acc[r], msk);
    if (lane == 0)
#pragma unroll
        for (int r = 0; r < 16; ++r) red[w][r] = acc[r];
    __syncthreads();
    if (tx < 16) {
        float v = 2.0f * (red[0][tx] + red[1][tx] + red[2][tx] + red[3][tx]);
        us h, l; split2(v, h, l);
        xq[(size_t)m * KP + 1024 + tx] = h;
        xq[(size_t)m * KP + 1040 + tx] = l;
    } else if (tx == 16) {
        xq[(size_t)m * KP + 1056] = 0x3F80;   // bias col = 1.0
    } else if (tx < 48) {
        xq[(size_t)m * KP + 1040 + tx] = 0;   // pads 1057..1087
    }
}

// weight quant + fold activation-scale residual: W' = Wq*(1+rho_c); split hi/lo.
__global__ __launch_bounds__(256) void k_quant_w(const float* __restrict__ W, const float* __restrict__ lB,
                                                 const float* __restrict__ bias,
                                                 const unsigned* __restrict__ smax,
                                                 us* __restrict__ wh, us* __restrict__ wl, int Nn) {
    __shared__ float red[4];
    int n = blockIdx.x, tx = threadIdx.x;
    int lane = tx & 63, w = tx >> 6;
    float4 wv = ((const float4*)(W + (size_t)n * DD))[tx];
    float m4 = fmaxf(fmaxf(fabsf(wv.x), fabsf(wv.y)), fmaxf(fabsf(wv.z), fabsf(wv.w)));
#pragma unroll
    for (int msk = 1; msk < 64; msk <<= 1) m4 = fmaxf(m4, __shfl_xor(m4, msk));
    if (lane == 0) red[w] = m4;
    __syncthreads();
    float t = fmaxf(fmaxf(fmaxf(red[0], red[1]), fmaxf(red[2], red[3])), 1e-8f);
    float vv[4] = {wv.x, wv.y, wv.z, wv.w};
    int c = tx * 4;
    ushort4 qh, ql;
    us* ph = (us*)&qh; us* pl = (us*)&ql;
#pragma unroll
    for (int j = 0; j < 4; ++j) {
        float s = fmaxf(__uint_as_float(smax[c + j]), 1e-8f);
        float sh = bf2f(f2bf(s));
        float rho = (s - sh) / sh;
        float q = logq_exact(vv[j], t);
        float wp = q + q * rho;
        split2(wp, ph[j], pl[j]);
    }
    *(ushort4*)(wh + (size_t)n * KP + c) = qh;
    *(ushort4*)(wl + (size_t)n * KP + c) = ql;
    if (tx < 64) {
        us h = 0, l = 0;
        if (tx < 32) { int r = tx & 15; split2(lB[(size_t)r * Nn + n], h, l); }
        else if (tx == 32) split2(bias[n], h, l);
        wh[(size_t)n * KP + 1024 + tx] = h;
        wl[(size_t)n * KP + 1024 + tx] = l;
    }
}

// ---------------- GEMM: C = Ah @ (W'h + W'l)^T, 2 MFMA passes ----------------
// 8-wave (512t) BM=256 BN=128 BK=64; 2 sub-phases per K-tile; counted vmcnt(8);
// STAGE(t+2) overlapped with ksub1 MFMA; XOR-granule swizzle (g ^= row&7) both-sides.
// MODE 0: linear f32 C[M][Nn].  MODE 1: qkv epilogue — q f32, v f32, k*SCL split bf16 [bh][s][64].

template <int MODE>
__global__ __launch_bounds__(512, 2) void k_gemm(const us* __restrict__ Aq_,
                                                 const us* __restrict__ Bh_, const us* __restrict__ Bl_,
                                                 float* __restrict__ C, int Nn,
                                                 us* __restrict__ Khg, us* __restrict__ Klg,
                                                 float* __restrict__ vbuf) {
    __shared__ us LA[2][16384];    // A 256x64 bf16 per buf (64KB total)
    __shared__ us LBh[2][8192];    // Bh 128x64 (32KB)
    __shared__ us LBl[2][8192];    // Bl 128x64 (32KB)
    int tid = threadIdx.x;
    int bm = blockIdx.x, bn = blockIdx.y;
    int lane = tid & 63, w = tid >> 6;
    int wm = w >> 2, wn = w & 3;             // 2 x 4 wave grid; per-wave out 128x32
    int l15 = lane & 15, l4 = lane >> 4;
    // staging: thread covers row srow(+64*i), dest granule tid&7; source pre-swizzled
    int srow = tid >> 3;
    int gsrc = ((tid & 7) ^ (srow & 7)) * 8;
    const us* aP  = Aq_ + (size_t)(bm * 256 + srow) * KP + gsrc;
    const us* bhP = Bh_ + (size_t)(bn * 128 + srow) * KP + gsrc;
    const us* blP = Bl_ + (size_t)(bn * 128 + srow) * KP + gsrc;
    f32x4 zero4 = {0.f, 0.f, 0.f, 0.f};
    f32x4 acc[8][2];
#pragma unroll
    for (int i = 0; i < 8; ++i) { acc[i][0] = zero4; acc[i][1] = zero4; }

#define GSTAGE(buf, kt)                                               \
    do {                                                              \
        int k0_ = (kt) * 64;                                          \
        gll16(aP + k0_,                    &LA[(buf)][0]     + tid * 8); \
        gll16(aP + (size_t)64  * KP + k0_, &LA[(buf)][4096]  + tid * 8); \
        gll16(aP + (size_t)128 * KP + k0_, &LA[(buf)][8192]  + tid * 8); \
        gll16(aP + (size_t)192 * KP + k0_, &LA[(buf)][12288] + tid * 8); \
        gll16(bhP + k0_,                   &LBh[(buf)][0]    + tid * 8); \
        gll16(bhP + (size_t)64 * KP + k0_, &LBh[(buf)][4096] + tid * 8); \
        gll16(blP + k0_,                   &LBl[(buf)][0]    + tid * 8); \
        gll16(blP + (size_t)64 * KP + k0_, &LBl[(buf)][4096] + tid * 8); \
    } while (0)

    GSTAGE(0, 0);
    GSTAGE(1, 1);
    WAITVM(8);
    __builtin_amdgcn_s_barrier();
    __builtin_amdgcn_sched_barrier(0);

    int gsw0 = ((l4)     ^ (l15 & 7)) * 8;   // ksub0 granule (swizzled), elements
    int gsw1 = ((4 + l4) ^ (l15 & 7)) * 8;   // ksub1
    int cur = 0;
    for (int kt = 0; kt < NT64; ++kt) {
        const us* A0  = &LA[cur][0];
        const us* Bh0 = &LBh[cur][0];
        const us* Bl0 = &LBl[cur][0];
        // ---- sub-phase 0 ----
        bf16x8 a0[8], b0h[2], b0l[2];
#pragma unroll
        for (int i = 0; i < 8; ++i)
            a0[i] = *(const bf16x8*)(A0 + (wm * 128 + i * 16 + l15) * 64 + gsw0);
#pragma unroll
        for (int i = 0; i < 2; ++i) {
            b0h[i] = *(const bf16x8*)(Bh0 + (wn * 32 + i * 16 + l15) * 64 + gsw0);
            b0l[i] = *(const bf16x8*)(Bl0 + (wn * 32 + i * 16 + l15) * 64 + gsw0);
        }
        __builtin_amdgcn_s_setprio(1);
#pragma unroll
        for (int mi = 0; mi < 8; ++mi)
#pragma unroll
            for (int ni = 0; ni < 2; ++ni) {
                acc[mi][ni] = __builtin_amdgcn_mfma_f32_16x16x32_bf16(a0[mi], b0h[ni], acc[mi][ni], 0, 0, 0);
                acc[mi][ni] = __builtin_amdgcn_mfma_f32_16x16x32_bf16(a0[mi], b0l[ni], acc[mi][ni], 0, 0, 0);
            }
        __builtin_amdgcn_s_setprio(0);
        // ---- sub-phase 1 reads ----
        bf16x8 a1[8], b1h[2], b1l[2];
#pragma unroll
        for (int i = 0; i < 8; ++i)
            a1[i] = *(const bf16x8*)(A0 + (wm * 128 + i * 16 + l15) * 64 + gsw1);
#pragma unroll
        for (int i = 0; i < 2; ++i) {
            b1h[i] = *(const bf16x8*)(Bh0 + (wn * 32 + i * 16 + l15) * 64 + gsw1);
            b1l[i] = *(const bf16x8*)(Bl0 + (wn * 32 + i * 16 + l15) * 64 + gsw1);
        }
        WAITLGKM0;                          // this wave done reading buf[cur]
        __builtin_amdgcn_sched_barrier(0);
        __builtin_amdgcn_s_barrier();       // all waves done reading buf[cur]
        __builtin_amdgcn_sched_barrier(0);
        if (kt + 2 < NT64) GSTAGE(cur, kt + 2);   // restage freed buffer; overlaps MFMA below
        __builtin_amdgcn_s_setprio(1);
#pragma unroll
        for (int mi = 0; mi < 8; ++mi)
#pragma unroll
            for (int ni = 0; ni < 2; ++ni) {
                acc[mi][ni] = __builtin_amdgcn_mfma_f32_16x16x32_bf16(a1[mi], b1h[ni], acc[mi][ni], 0, 0, 0);
                acc[mi][ni] = __builtin_amdgcn_mfma_f32_16x16x32_bf16(a1[mi], b1l[ni], acc[mi][ni], 0, 0, 0);
            }
        __builtin_amdgcn_s_setprio(0);
        if (kt + 2 < NT64) { WAITVM(8); } else { WAITVM(0); }   // tile kt+1 landed
        __builtin_amdgcn_s_barrier();
        __builtin_amdgcn_sched_barrier(0);
        cur ^= 1;
    }
#undef GSTAGE

    int plane = bn >> 3;   // MODE 1 only; block-uniform
#pragma unroll
    for (int mi = 0; mi < 8; ++mi) {
#pragma unroll
        for (int ni = 0; ni < 2; ++ni) {
            int ncol = bn * 128 + wn * 32 + ni * 16 + l15;
            size_t mbase = (size_t)bm * 256 + wm * 128 + mi * 16 + l4 * 4;
#pragma unroll
            for (int rr = 0; rr < 4; ++rr) {
                float v = acc[mi][ni][rr];
                size_t m = mbase + rr;
                if (MODE == 0) {
                    C[m * (size_t)Nn + ncol] = v;
                } else {
                    int cc = ncol & 1023;
                    if (plane == 0) {
                        C[m * DD + cc] = v;
                    } else if (plane == 2) {
                        vbuf[m * DD + cc] = v;
                    } else {
                        us hh, ll; split2(v * SCL, hh, ll);   // fold softmax scale into K
                        size_t d = ((size_t)((m >> 11) * 16 + (cc >> 6)) * SS + (m & 2047)) * 64 + (cc & 63);
                        Khg[d] = hh; Klg[d] = ll;
                    }
                }
            }
        }
    }
}

// ---------------- V transpose+split: vbuf f32 -> vth/vtl [bh][hd][s-permuted] bf16 ----------------

__global__ __launch_bounds__(256) void k_transpose_v(const float* __restrict__ vbuf,
                                                     us* __restrict__ vth, us* __restrict__ vtl) {
    __shared__ us th[64][72], tl[64][72];
    int st = blockIdx.x, bh = blockIdx.y;
    int bb = bh >> 4, h = bh & 15;
    int s0 = st * 64, tid = threadIdx.x;
    int sl = tid >> 2, c0 = (tid & 3) * 16;
    const float* src = vbuf + (size_t)(bb * SS + s0 + sl) * DD + h * 64 + c0;
#pragma unroll
    for (int j4 = 0; j4 < 4; ++j4) {
        float4 v = *(const float4*)(src + j4 * 4);
        float vv[4] = {v.x, v.y, v.z, v.w};
#pragma unroll
        for (int j = 0; j < 4; ++j) {
            us hh, ll; split2(vv[j], hh, ll);
            th[c0 + j4 * 4 + j][sl] = hh;
            tl[c0 + j4 * 4 + j][sl] = ll;
        }
    }
    __syncthreads();
#pragma unroll
    for (int p = 0; p < 2; ++p) {
        int gidx = p * 256 + tid;
        int hd = gidx >> 3, g = gidx & 7;
        int base = (g >> 2) * 32 + (g & 3) * 4;
        ushort4 a, b2, c, d2;
        a.x = th[hd][base];      a.y = th[hd][base + 1];  a.z = th[hd][base + 2];  a.w = th[hd][base + 3];
        b2.x = th[hd][base + 16]; b2.y = th[hd][base + 17]; b2.z = th[hd][base + 18]; b2.w = th[hd][base + 19];
        c.x = tl[hd][base];      c.y = tl[hd][base + 1];  c.z = tl[hd][base + 2];  c.w = tl[hd][base + 3];
        d2.x = tl[hd][base + 16]; d2.y = tl[hd][base + 17]; d2.z = tl[hd][base + 18]; d2.w = tl[hd][base + 19];
        size_t dof = ((size_t)bh * 64 + hd) * SS + s0 + g * 8;
        *(ushort4*)(vth + dof) = a;  *(ushort4*)(vth + dof + 4) = b2;
        *(ushort4*)(vtl + dof) = c;  *(ushort4*)(vtl + dof + 4) = d2;
    }
}

// ---------------- causal flash attention; counted-vmcnt pipeline; defer-max softmax ----------------
// output written IN-PLACE into the q plane; K plane pre-scaled by SCL.

__global__ __launch_bounds__(256, 2) void k_attn(float* qo,
                                                 const us* __restrict__ Khg, const us* __restrict__ Klg,
                                                 const us* __restrict__ vth, const us* __restrict__ vtl) {
    __shared__ us L[2][16384];  // per buf: [0]=Kh [4096]=Kl [8192]=Vh [12288]=Vl, 64x64 bf16, XOR-8 swz
    int bh = blockIdx.x;
    int qt = (int)(gridDim.y - 1) - blockIdx.y;   // heavy q-tiles first
    int b = bh >> 4, h = bh & 15;
    int q0 = qt * 128;
    int tid = threadIdx.x, w = tid >> 6, lane = tid & 63;
    int l15 = lane & 15, l4 = lane >> 4;
    int qw = q0 + w * 32;
    int swz = l15 & 7;

    bf16x8 qh[2][2], ql[2][2];
#pragma unroll
    for (int qb = 0; qb < 2; ++qb)
#pragma unroll
        for (int hf = 0; hf < 2; ++hf) {
            const float* qp = qo + (size_t)(b * SS + qw + qb * 16 + l15) * DD + h * 64 + hf * 32 + l4 * 8;
            float4 a = *(const float4*)qp;
            float4 c = *(const float4*)(qp + 4);
            float vv[8] = {a.x, a.y, a.z, a.w, c.x, c.y, c.z, c.w};
            bf16x8 hq, lq;
#pragma unroll
            for (int j = 0; j < 8; ++j) {
                us hh = f2bf(vv[j]);
                hq[j] = (short)hh;
                lq[j] = (short)f2bf(vv[j] - bf2f(hh));
            }
            qh[qb][hf] = hq; ql[qb][hf] = lq;
        }

    f32x4 zero4 = {0.f, 0.f, 0.f, 0.f};
    f32x4 of[2][4];
#pragma unroll
    for (int i = 0; i < 2; ++i)
#pragma unroll
        for (int j = 0; j < 4; ++j) of[i][j] = zero4;
    float mrow[2] = {-1e30f, -1e30f}, lrowp[2] = {0.f, 0.f};   // lrowp: per-lane partial

    int r0 = tid >> 3, sl0 = (tid & 7) ^ (r0 & 7);
    int g1 = tid + 256, r1 = g1 >> 3, sl1 = (g1 & 7) ^ (r1 & 7);
    int koff0 = (bh * SS + r0) * 64 + sl0 * 8;
    int koff1 = (bh * SS + r1) * 64 + sl1 * 8;
    int voff0 = (bh * 64 + r0) * SS + sl0 * 8;
    int voff1 = (bh * 64 + r1) * SS + sl1 * 8;

    int ntiles = qt * 2 + 2;

#define STAGE(buf, tt)                                           \
    do {                                                         \
        int kv_ = (tt) * 64;                                     \
        us* D_ = &L[(buf)][0];                                   \
        int kadd_ = kv_ << 6;                                    \
        gll16(Khg + koff0 + kadd_, D_ + tid * 8);                \
        gll16(Khg + koff1 + kadd_, D_ + 2048 + tid * 8);         \
        gll16(Klg + koff0 + kadd_, D_ + 4096 + tid * 8);         \
        gll16(Klg + koff1 + kadd_, D_ + 6144 + tid * 8);         \
        gll16(vth + voff0 + kv_, D_ + 8192 + tid * 8);           \
        gll16(vth + voff1 + kv_, D_ + 10240 + tid * 8);          \
        gll16(vtl + voff0 + kv_, D_ + 12288 + tid * 8);          \
        gll16(vtl + voff1 + kv_, D_ + 14336 + tid * 8);          \
    } while (0)

    STAGE(0, 0);
    STAGE(1, 1);
    int cur = 0;

    for (int t = 0; t < ntiles; ++t) {
        int kv0 = t * 64;
        if (t + 1 < ntiles) WAITVM(8); else WAITVM(0);
        __builtin_amdgcn_s_barrier();

        if (kv0 <= qw + 31) {
            const us* Lc = &L[cur][0];

            f32x4 sf[4][2];
#pragma unroll
            for (int i = 0; i < 4; ++i) { sf[i][0] = zero4; sf[i][1] = zero4; }
            __builtin_amdgcn_s_setprio(1);
#pragma unroll
            for (int kb = 0; kb < 4; ++kb) {
                int rbase = (kb * 16 + l15) * 64;
#pragma unroll
                for (int hf = 0; hf < 2; ++hf) {
                    int off = rbase + (((hf * 4 + l4) ^ swz) * 8);
                    bf16x8 kh = *(const bf16x8*)(Lc + off);
                    bf16x8 kl = *(const bf16x8*)(Lc + 4096 + off);
#pragma unroll
                    for (int qb = 0; qb < 2; ++qb) {
                        sf[kb][qb] = __builtin_amdgcn_mfma_f32_16x16x32_bf16(kh, qh[qb][hf], sf[kb][qb], 0, 0, 0);
                        sf[kb][qb] = __builtin_amdgcn_mfma_f32_16x16x32_bf16(kh, ql[qb][hf], sf[kb][qb], 0, 0, 0);
                        sf[kb][qb] = __builtin_amdgcn_mfma_f32_16x16x32_bf16(kl, qh[qb][hf], sf[kb][qb], 0, 0, 0);
                    }
                }
            }
            __builtin_amdgcn_s_setprio(0);

            bool diag = (kv0 + 63 > qw);   // wave-uniform
            u32x4 PH[2][2], PL[2][2];
#pragma unroll
            for (int qb = 0; qb < 2; ++qb) {
                float pv[16];
                if (diag) {
                    int qg = qw + qb * 16 + l15;
#pragma unroll
                    for (int kb = 0; kb < 4; ++kb)
#pragma unroll
                        for (int rr = 0; rr < 4; ++rr) {
                            int kvg = kv0 + kb * 16 + l4 * 4 + rr;
                            pv[kb * 4 + rr] = (kvg > qg) ? -1e30f : sf[kb][qb][rr];
                        }
                } else {
#pragma unroll
                    for (int kb = 0; kb < 4; ++kb)
#pragma unroll
                        for (int rr = 0; rr < 4; ++rr)
                            pv[kb * 4 + rr] = sf[kb][qb][rr];
                }
                // max3-shaped reduction tree
                float t0 = fmaxf(fmaxf(pv[0], pv[1]), pv[2]);
                float t1 = fmaxf(fmaxf(pv[3], pv[4]), pv[5]);
                float t2 = fmaxf(fmaxf(pv[6], pv[7]), pv[8]);
                float t3 = fmaxf(fmaxf(pv[9], pv[10]), pv[11]);
                float t4 = fmaxf(fmaxf(pv[12], pv[13]), pv[14]);
                float tmax = fmaxf(fmaxf(fmaxf(t0, t1), fmaxf(t2, t3)), fmaxf(t4, pv[15]));
                tmax = fmaxf(tmax, __shfl_xor(tmax, 16));
                tmax = fmaxf(tmax, __shfl_xor(tmax, 32));
                float mcur = mrow[qb];
                if (!__all(tmax <= mcur + 8.0f)) {   // defer-max: exact (fac==1 when skipped)
                    float mnew = fmaxf(mcur, tmax);
                    float fac = __builtin_amdgcn_exp2f(mcur - mnew);
                    mrow[qb] = mnew; mcur = mnew;
                    lrowp[qb] *= fac;
                    float fr0 = __shfl(fac, l4 * 4 + 0);
                    float fr1 = __shfl(fac, l4 * 4 + 1);
                    float fr2 = __shfl(fac, l4 * 4 + 2);
                    float fr3 = __shfl(fac, l4 * 4 + 3);
#pragma unroll
                    for (int hb = 0; hb < 4; ++hb) {
                        of[qb][hb][0] *= fr0; of[qb][hb][1] *= fr1;
                        of[qb][hb][2] *= fr2; of[qb][hb][3] *= fr3;
                    }
                }
                float ps = 0.f;
#pragma unroll
                for (int i = 0; i < 16; ++i) {
                    pv[i] = __builtin_amdgcn_exp2f(pv[i] - mcur);
                    ps += pv[i];
                }
                lrowp[qb] += ps;                 // per-lane partial; cross-lane at epilogue
#pragma unroll
                for (int ks = 0; ks < 2; ++ks)
#pragma unroll
                    for (int c2 = 0; c2 < 4; ++c2) {
                        float p0 = pv[ks * 8 + c2 * 2], p1 = pv[ks * 8 + c2 * 2 + 1];
                        unsigned u = cvtpk(p0, p1);
                        float h0 = __uint_as_float(u << 16);
                        float h1 = __uint_as_float(u & 0xffff0000u);
                        unsigned ul = cvtpk(p0 - h0, p1 - h1);
                        PH[qb][ks][c2] = u; PL[qb][ks][c2] = ul;
                    }
            }

            __builtin_amdgcn_s_setprio(1);
#pragma unroll
            for (int hb = 0; hb < 4; ++hb) {
                int rbase = (hb * 16 + l15) * 64;
#pragma unroll
                for (int ks = 0; ks < 2; ++ks) {
                    int off = rbase + (((ks * 4 + l4) ^ swz) * 8);
                    bf16x8 vh = *(const bf16x8*)(Lc + 8192 + off);
                    bf16x8 vl = *(const bf16x8*)(Lc + 12288 + off);
#pragma unroll
                    for (int qb = 0; qb < 2; ++qb) {
                        bf16x8 pa = (bf16x8)PH[qb][ks];
                        bf16x8 pb = (bf16x8)PL[qb][ks];
                        of[qb][hb] = __builtin_amdgcn_mfma_f32_16x16x32_bf16(pa, vh, of[qb][hb], 0, 0, 0);
                        of[qb][hb] = __builtin_amdgcn_mfma_f32_16x16x32_bf16(pa, vl, of[qb][hb], 0, 0, 0);
                        of[qb][hb] = __builtin_amdgcn_mfma_f32_16x16x32_bf16(pb, vh, of[qb][hb], 0, 0, 0);
                    }
                }
            }
            __builtin_amdgcn_s_setprio(0);
        }

        __builtin_amdgcn_s_barrier();
        if (t + 2 < ntiles) STAGE(cur, t + 2);
        cur ^= 1;
    }
#undef STAGE

#pragma unroll
    for (int qb = 0; qb < 2; ++qb) {
        float lr = lrowp[qb];
        lr += __shfl_xor(lr, 16);
        lr += __shfl_xor(lr, 32);
        float linv = 1.f / lr;
        float f0 = __shfl(linv, l4 * 4 + 0);
        float f1 = __shfl(linv, l4 * 4 + 1);
        float f2 = __shfl(linv, l4 * 4 + 2);
        float f3 = __shfl(linv, l4 * 4 + 3);
        int qgb = qw + qb * 16 + l4 * 4;
#pragma unroll
        for (int hb = 0; hb < 4; ++hb) {
            int col = h * 64 + hb * 16 + l15;
            qo[((size_t)(b * SS + qgb + 0)) * DD + col] = of[qb][hb][0] * f0;
            qo[((size_t)(b * SS + qgb + 1)) * DD + col] = of[qb][hb][1] * f1;
            qo[((size_t)(b * SS + qgb + 2)) * DD + col] = of[qb][hb][2] * f2;
            qo[((size_t)(b * SS + qgb + 3)) * DD + col] = of[qb][hb][3] * f3;
        }
    }
}

// ---------------- launcher ----------------

extern "C" void kernel_launch(void* const* d_in, const int* in_sizes, int n_in,
                              void* d_out, int out_size, void* d_ws, size_t ws_size,
                              hipStream_t stream) {
    const float* hidden  = (const float*)d_in[0];
    const float* W_attn  = (const float*)d_in[2];
    const float* b_attn  = (const float*)d_in[3];
    const float* lA_attn = (const float*)d_in[4];
    const float* lB_attn = (const float*)d_in[5];
    const float* W_proj  = (const float*)d_in[6];
    const float* b_proj  = (const float*)d_in[7];
    const float* lA_proj = (const float*)d_in[8];
    const float* lB_proj = (const float*)d_in[9];
    float* out = (float*)d_out;

    char* ws = (char*)d_ws;
    unsigned* s1 = (unsigned*)(ws);
    unsigned* s2 = (unsigned*)(ws + 4096);
    us* xq  = (us*)(ws + 8192);                              // 17,825,792 B (8192x1088x2)
    us* vth = xq;                                            // overlay (phase B: xq dead)
    us* wh1 = (us*)(ws + 8192 + 17825792);                   // 6,684,672
    us* wl1 = (us*)(ws + 8192 + 17825792 + 6684672);         // 6,684,672
    us* wh2 = (us*)(ws + 8192 + 17825792 + 2 * 6684672);     // 2,228,224
    us* wl2 = (us*)(ws + 8192 + 17825792 + 2 * 6684672 + 2228224);
    char* pbase = ws + 8192 + 17825792 + 2 * 6684672 + 2 * 2228224;
    float* qbuf = (float*)pbase;                             // 33,554,432 (q plane; attn out in-place)
    float* vbuf = (float*)(pbase + 33554432);                // 33,554,432 (v plane, dead after transpose)
    us* Khg = (us*)(pbase + 2 * (size_t)33554432);           // 16,777,216
    us* Klg = (us*)(pbase + 2 * (size_t)33554432 + 16777216);
    us* vtl = (us*)(pbase + 2 * (size_t)33554432 + 2 * (size_t)16777216);  // 16,777,216

    k_zero<<<8, 256, 0, stream>>>(s1, 2048);

    // ---- qkv projection ----
    k_colmax<<<dim3(4, 64), 256, 0, stream>>>(hidden, s1);
    k_quant_lora<<<MTOT, 256, 0, stream>>>(hidden, s1, lA_attn, xq);
    k_quant_w<<<3072, 256, 0, stream>>>(W_attn, lB_attn, b_attn, s1, wh1, wl1, 3072);
    k_gemm<1><<<dim3(32, 24), 512, 0, stream>>>(xq, wh1, wl1, qbuf, DQKV, Khg, Klg, vbuf);

    // ---- attention (output in-place into qbuf) ----
    k_transpose_v<<<dim3(32, 64), 256, 0, stream>>>(vbuf, vth, vtl);
    k_attn<<<dim3(64, 16), 256, 0, stream>>>(qbuf, Khg, Klg, vth, vtl);

    // ---- output projection ----
    k_colmax<<<dim3(4, 64), 256, 0, stream>>>(qbuf, s2);
    k_quant_lora<<<MTOT, 256, 0, stream>>>(qbuf, s2, lA_proj, xq);
    k_quant_w<<<1024, 256, 0, stream>>>(W_proj, lB_proj, b_proj, s2, wh2, wl2, 1024);
    k_gemm<0><<<dim3(32, 8), 512, 0, stream>>>(xq, wh2, wl2, out, DD, nullptr, nullptr, nullptr);
}